// Round 16
// baseline (3042.953 us; speedup 1.0000x reference)
//
#include <hip/hip_runtime.h>

#define NB 8
#define NPTS 16384
#define M1 1024
#define NA 8192

// d_out float offsets
#define OUT_IP0  0
#define OUT_IP1  393216
#define OUT_OUT0 417792
#define OUT_OUT1 811008
#define OUT_Z    835584

typedef unsigned long long u64;

__device__ __forceinline__ float exact_d2(float ax, float ay, float az,
                                          float bx, float by, float bz) {
  float dx = __fsub_rn(ax, bx);
  float dy = __fsub_rn(ay, by);
  float dz = __fsub_rn(az, bz);
  return __fadd_rn(__fadd_rn(__fmul_rn(dx, dx), __fmul_rn(dy, dy)),
                   __fmul_rn(dz, dz));
}

__device__ __forceinline__ bool dl_lt(float d1, int i1, float d2, int i2) {
  return (d1 < d2) || ((d1 == d2) && (i1 < i2));
}

// DPP fmin step: old=SELF, bound_ctrl=0 -> OOB lanes combine self (no-op).
template <int CTRL>
__device__ __forceinline__ float dpp_fmin_self(float v) {
  const int s = __builtin_amdgcn_update_dpp(__float_as_int(v),
                                            __float_as_int(v), CTRL, 0xf, 0xf,
                                            false);
  return fminf(v, __int_as_float(s));
}

// DPP u64-min step (old=self).
template <int CTRL>
__device__ __forceinline__ u64 dpp_min_u64(u64 v) {
  const int lo = (int)(unsigned)v;
  const int hi = (int)(unsigned)(v >> 32);
  const int slo = __builtin_amdgcn_update_dpp(lo, lo, CTRL, 0xf, 0xf, false);
  const int shi = __builtin_amdgcn_update_dpp(hi, hi, CTRL, 0xf, 0xf, false);
  const u64 s = ((u64)(unsigned)shi << 32) | (unsigned)slo;
  return s < v ? s : v;
}

// DPP u64-max step (old=self).
template <int CTRL>
__device__ __forceinline__ u64 dpp_max_u64(u64 v) {
  const int lo = (int)(unsigned)v;
  const int hi = (int)(unsigned)(v >> 32);
  const int slo = __builtin_amdgcn_update_dpp(lo, lo, CTRL, 0xf, 0xf, false);
  const int shi = __builtin_amdgcn_update_dpp(hi, hi, CTRL, 0xf, 0xf, false);
  const u64 s = ((u64)(unsigned)shi << 32) | (unsigned)slo;
  return s > v ? s : v;
}

// ---------------- counting sort: spatial 16^3 bucketing per cloud -----------
// Scatter order within a bucket is atomic-order-dependent (nondeterministic)
// but harmless: fps selections depend only on exact per-point keys, so the
// OUTPUT is deterministic. Bucketing quality only affects skip rate.
__global__ __launch_bounds__(1024) void sort_kernel(
    const float* __restrict__ pts, int* __restrict__ perm) {
  const int b = blockIdx.x;
  const float* __restrict__ P = pts + (size_t)b * NPTS * 3;
  const int t = threadIdx.x;
  __shared__ int hist[4096];
  __shared__ int csum[64];
  for (int i = t; i < 4096; i += 1024) hist[i] = 0;
  __syncthreads();
  int cell[16];
#pragma unroll
  for (int j = 0; j < 16; ++j) {
    const int idx = t * 16 + j;
    const float x = P[idx * 3 + 0];
    const float y = P[idx * 3 + 1];
    const float z = P[idx * 3 + 2];
    int cx = (int)((x + 4.0f) * 2.0f); cx = cx < 0 ? 0 : (cx > 15 ? 15 : cx);
    int cy = (int)((y + 4.0f) * 2.0f); cy = cy < 0 ? 0 : (cy > 15 ? 15 : cy);
    int cz = (int)((z + 4.0f) * 2.0f); cz = cz < 0 ? 0 : (cz > 15 ? 15 : cz);
    const int c = (cx << 8) | (cy << 4) | cz;
    cell[j] = c;
    atomicAdd(&hist[c], 1);
  }
  __syncthreads();
  if (t < 64) {
    int s = 0;
    for (int i = 0; i < 64; ++i) s += hist[t * 64 + i];
    csum[t] = s;
  }
  __syncthreads();
  if (t == 0) {
    int run = 0;
    for (int i = 0; i < 64; ++i) { const int v = csum[i]; csum[i] = run; run += v; }
  }
  __syncthreads();
  if (t < 64) {
    int run = csum[t];
    for (int i = 0; i < 64; ++i) { const int v = hist[t * 64 + i]; hist[t * 64 + i] = run; run += v; }
  }
  __syncthreads();
#pragma unroll
  for (int j = 0; j < 16; ++j) {
    const int pos = atomicAdd(&hist[cell[j]], 1);
    perm[b * NPTS + pos] = t * 16 + j;
  }
}

// ---------------- FPS v12b: spatial chunks + provably-exact skip ------------
// r15 crash root cause: readlane(v,63) was INSIDE if(lane==0); compiler may
// sink the DPP chain into the divergent region -> lane63's copy of v never
// written -> readlane returns garbage -> wi garbage -> OOB fault. Fix:
// readlanes hoisted to convergent code (only atomicMax stays divergent);
// plus defensive wi &= NPTS-1 (no-op when correct, absmax-diagnosable if not).
// Skip bound: (dist(m,c)*0.995 - r)^2 * 0.98 >= bv with r = 1.01*max dist to
// chunk mean -> margins (~2.5%) dwarf fp error -> skip implies no dd change
// -> selections BIT-IDENTICAL. Owner of winner never skips (dist(m,c) <= r).
__global__ __launch_bounds__(1024) void fps_kernel(
    const float* __restrict__ pts, const int* __restrict__ perm,
    int* __restrict__ fidx) {
  const int b = blockIdx.x;
  const float* __restrict__ P = pts + (size_t)b * NPTS * 3;
  const int t = threadIdx.x;
  const int lane = t & 63;

  __shared__ u64 s_slot[3];
  __shared__ char s_pad[81920];  // occupancy governor (v10 best config)
  if ((int)blockIdx.x == -1) ((volatile char*)s_pad)[0] = 1;

  float px[16], py[16], pz[16], dd[16];
  int oi[16];
  const float sx = P[0], sy = P[1], sz = P[2];
  u64 kb = 0;
  float mx = 0.0f, my = 0.0f, mz = 0.0f;
#pragma unroll
  for (int j = 0; j < 16; ++j) {
    const int o = perm[b * NPTS + t * 16 + j];
    oi[j] = o;
    const float x = P[o * 3 + 0];
    const float y = P[o * 3 + 1];
    const float z = P[o * 3 + 2];
    px[j] = x; py[j] = y; pz[j] = z;
    mx += x; my += y; mz += z;
    const float d = exact_d2(x, y, z, sx, sy, sz);
    dd[j] = d;
    const u64 k = ((u64)__float_as_uint(d) << 32) | (u64)(~(unsigned)o);
    if (k > kb) kb = k;
  }
  mx *= 0.0625f; my *= 0.0625f; mz *= 0.0625f;
  float r2m = 0.0f;
#pragma unroll
  for (int j = 0; j < 16; ++j) {
    const float dx = px[j] - mx, dy = py[j] - my, dz = pz[j] - mz;
    const float r2 = fmaf(dx, dx, fmaf(dy, dy, dz * dz));
    r2m = fmaxf(r2m, r2);
  }
  const float r = sqrtf(r2m) * 1.01f;  // safe UPPER bound on max dist(p_j, m)

  if (t == 0) {
    fidx[b * M1 + 0] = 0;
    s_slot[0] = 0; s_slot[1] = 0; s_slot[2] = 0;
  }
  __syncthreads();

  for (int it = 1; it < M1; ++it) {
    const int par = it % 3;
    const int nxt = (it + 1) % 3;
    // ---- wave reduce on u64 key (DPP, exact ties); ALL CONVERGENT ----
    u64 v = kb;
    v = dpp_max_u64<0x111>(v);
    v = dpp_max_u64<0x112>(v);
    v = dpp_max_u64<0x114>(v);
    v = dpp_max_u64<0x118>(v);
    v = dpp_max_u64<0x142>(v);
    v = dpp_max_u64<0x143>(v);
    // readlanes in convergent code (r15 fix)
    const unsigned wlo =
        (unsigned)__builtin_amdgcn_readlane((int)(unsigned)v, 63);
    const unsigned whi =
        (unsigned)__builtin_amdgcn_readlane((int)(unsigned)(v >> 32), 63);
    if (lane == 0) atomicMax(&s_slot[par], ((u64)whi << 32) | wlo);
    if (t == 0) s_slot[nxt] = 0;
    __syncthreads();
    const u64 g = s_slot[par];
    const int wi =
        __builtin_amdgcn_readfirstlane((int)(~(unsigned)g)) & (NPTS - 1);
    if (t == 0) fidx[b * M1 + it] = wi;
    const float cx = P[wi * 3 + 0];  // uniform -> scalar loads
    const float cy = P[wi * 3 + 1];
    const float cz = P[wi * 3 + 2];
    // ---- conservative skip bound ----
    const float bvf = __uint_as_float((unsigned)(kb >> 32));
    const float ex = mx - cx, ey = my - cy, ez = mz - cz;
    const float d2mc = fmaf(ex, ex, fmaf(ey, ey, ez * ez));
    const float s = sqrtf(d2mc);
    const float lb = fmaf(s, 0.995f, -r);  // safe LOWER bound on dist(p_j,c)
    const bool skip = (lb > 0.0f) && (lb * lb * 0.98f >= bvf);
    if (!skip) {
      kb = 0;
#pragma unroll
      for (int j = 0; j < 16; ++j) {
        const float d2 = exact_d2(px[j], py[j], pz[j], cx, cy, cz);
        const float nd = fminf(dd[j], d2);
        dd[j] = nd;
        const u64 k =
            ((u64)__float_as_uint(nd) << 32) | (u64)(~(unsigned)oi[j]);
        if (k > kb) kb = k;
      }
    }
  }
}

// ---------------- gather p1 (also output ip1) -------------------------------
__global__ void gather_p1_kernel(const float* __restrict__ pts,
                                 const int* __restrict__ fidx,
                                 float* __restrict__ p1,
                                 float* __restrict__ out_ip1) {
  const int i = blockIdx.x * 256 + threadIdx.x;
  if (i >= NA * 3) return;
  const int a = i / 3, c = i - a * 3;
  const int b = a >> 10;
  const int src = fidx[a];
  const float v = pts[((size_t)b * NPTS + src) * 3 + c];
  p1[i] = v;
  out_ip1[i] = v;
}

// ---------------- KNN v2: DPP everywhere (r13 WIN) --------------------------
__global__ __launch_bounds__(256) void knn_kernel(
    const float* __restrict__ pts, const float* __restrict__ p1,
    int* __restrict__ knn_i, float* __restrict__ knn_d,
    float* __restrict__ out_ip0) {
  const int wq = threadIdx.x >> 6;
  const int lane = threadIdx.x & 63;
  const int a = blockIdx.x * 4 + wq;
  const int b = a >> 10;
  const float* __restrict__ P = pts + (size_t)b * NPTS * 3;
  const float qx = p1[a * 3 + 0], qy = p1[a * 3 + 1], qz = p1[a * 3 + 2];
  const float INF = __builtin_inff();
  float D[16]; int I[16];
#pragma unroll
  for (int s = 0; s < 16; ++s) { D[s] = INF; I[s] = 0x7fffffff; }
  float wstar = INF;

  for (int s = 0; s < NPTS / 64; ++s) {
    const int idx = s * 64 + lane;
    const float x = P[idx * 3 + 0];
    const float y = P[idx * 3 + 1];
    const float z = P[idx * 3 + 2];
    const float d2 = exact_d2(x, y, z, qx, qy, qz);
    const bool pass = (d2 <= wstar);
    if (__any(pass)) {
      if (pass && dl_lt(d2, idx, D[15], I[15])) {
        bool c[16];
#pragma unroll
        for (int u = 0; u < 16; ++u) c[u] = dl_lt(d2, idx, D[u], I[u]);
#pragma unroll
        for (int u = 15; u >= 1; --u) {
          D[u] = c[u] ? (c[u - 1] ? D[u - 1] : d2) : D[u];
          I[u] = c[u] ? (c[u - 1] ? I[u - 1] : idx) : I[u];
        }
        if (c[0]) { D[0] = d2; I[0] = idx; }
      }
      float w = D[15];
      w = dpp_fmin_self<0x111>(w);
      w = dpp_fmin_self<0x112>(w);
      w = dpp_fmin_self<0x114>(w);
      w = dpp_fmin_self<0x118>(w);
      w = dpp_fmin_self<0x142>(w);
      w = dpp_fmin_self<0x143>(w);
      wstar = __int_as_float(
          __builtin_amdgcn_readlane(__float_as_int(w), 63));
    }
  }

  __shared__ u64 sk[4][1024];
#pragma unroll
  for (int u = 0; u < 16; ++u)
    sk[wq][lane * 16 + u] =
        ((u64)__float_as_uint(D[u]) << 32) | (unsigned)I[u];
  int head = lane * 16;
  const int hend = head + 16;
  u64 md = sk[wq][head];
  u64 outK = 0;
  for (int r = 0; r < 16; ++r) {
    u64 v = md;
    v = dpp_min_u64<0x111>(v);
    v = dpp_min_u64<0x112>(v);
    v = dpp_min_u64<0x114>(v);
    v = dpp_min_u64<0x118>(v);
    v = dpp_min_u64<0x142>(v);
    v = dpp_min_u64<0x143>(v);
    const unsigned glo =
        (unsigned)__builtin_amdgcn_readlane((int)(unsigned)v, 63);
    const unsigned ghi =
        (unsigned)__builtin_amdgcn_readlane((int)(unsigned)(v >> 32), 63);
    const u64 g = ((u64)ghi << 32) | glo;
    if (lane == r) outK = g;
    if (md == g) {
      ++head;
      md = (head < hend) ? sk[wq][head] : ~0ull;
    }
  }
  if (lane < 16) {
    const int o = a * 16 + lane;
    const int outI = (int)(unsigned)outK;
    knn_i[o] = outI;
    knn_d[o] = __uint_as_float((unsigned)(outK >> 32));
    out_ip0[(size_t)o * 3 + 0] = P[outI * 3 + 0];
    out_ip0[(size_t)o * 3 + 1] = P[outI * 3 + 1];
    out_ip0[(size_t)o * 3 + 2] = P[outI * 3 + 2];
  }
}

// ---------------- encoder 0: per-anchor shared MLP + max pool ---------------
__global__ __launch_bounds__(128) void enc0_kernel(
    const float* __restrict__ ip0, const float* __restrict__ knn_d,
    const float* __restrict__ p1, const float* __restrict__ W0a,
    const float* __restrict__ b0a, const float* __restrict__ W0b,
    const float* __restrict__ b0b, float* __restrict__ f0) {
  const int a = blockIdx.x;
  __shared__ float rel[16][4];
  __shared__ __align__(16) float h1s[16][64];
  const int t = threadIdx.x;
  if (t < 16) {
    const float ax = p1[a * 3 + 0], ay = p1[a * 3 + 1], az = p1[a * 3 + 2];
    const float kd = knn_d[a * 16 + t];
    const bool within = (kd <= 0.04f);
    const float* nb = ip0 + (size_t)(a * 16 + t) * 3;
    rel[t][0] = within ? (nb[0] - ax) * 5.0f : 0.0f;
    rel[t][1] = within ? (nb[1] - ay) * 5.0f : 0.0f;
    rel[t][2] = within ? (nb[2] - az) * 5.0f : 0.0f;
  }
  __syncthreads();
  {
    const int m = t & 63, kh = t >> 6;
    const float w0 = W0a[m], w1 = W0a[64 + m], w2 = W0a[128 + m];
    const float bb = b0a[m];
#pragma unroll
    for (int kk = 0; kk < 8; ++kk) {
      const int k = kh * 8 + kk;
      const float h =
          fmaf(rel[k][0], w0, fmaf(rel[k][1], w1, fmaf(rel[k][2], w2, bb)));
      h1s[k][m] = fmaxf(h, 0.0f);
    }
  }
  __syncthreads();
  {
    const int col = t;  // 0..127
    float acc[16];
#pragma unroll
    for (int k = 0; k < 16; ++k) acc[k] = 0.0f;
    for (int m = 0; m < 64; m += 4) {
      const float w0 = W0b[(m + 0) * 128 + col];
      const float w1 = W0b[(m + 1) * 128 + col];
      const float w2 = W0b[(m + 2) * 128 + col];
      const float w3 = W0b[(m + 3) * 128 + col];
#pragma unroll
      for (int k = 0; k < 16; ++k) {
        const float4 h = *(const float4*)&h1s[k][m];
        acc[k] = fmaf(h.x, w0, fmaf(h.y, w1, fmaf(h.z, w2, fmaf(h.w, w3, acc[k]))));
      }
    }
    float mx = acc[0];
#pragma unroll
    for (int k = 1; k < 16; ++k) mx = fmaxf(mx, acc[k]);
    f0[(size_t)a * 128 + col] = mx + b0b[col];
  }
}

// ---------------- build X1 = [p1*2 | f0 | 0pad] ------------------------------
__global__ void build_x1_kernel(const float* __restrict__ p1,
                                const float* __restrict__ f0,
                                float* __restrict__ X1) {
  const int i = blockIdx.x * 256 + threadIdx.x;
  if (i >= NA * 132) return;
  const int r = i / 132, c = i - r * 132;
  float v;
  if (c < 3) v = p1[r * 3 + c] * 2.0f;
  else if (c < 131) v = f0[(size_t)r * 128 + (c - 3)];
  else v = 0.0f;
  X1[i] = v;
}

// ---------------- generic 64x64 fp32 GEMM (+bias, optional relu/colmax) -----
template <int DO_RELU, int COLMAX>
__global__ __launch_bounds__(256) void gemm64_kernel(
    const float* __restrict__ A, const float* __restrict__ W,
    const float* __restrict__ bias, float* __restrict__ C, const int N,
    const int K, const int Kreal, const int lda, const int ldb) {
  __shared__ float As[64][33];
  __shared__ __align__(16) float Bs[32][64];
  __shared__ float red[16][64];
  const int t = threadIdx.x;
  const int tx = t & 15, ty = t >> 4;
  const int row0 = blockIdx.y * 64, col0 = blockIdx.x * 64;
  float acc[4][4] = {};
  for (int k0 = 0; k0 < K; k0 += 32) {
    {
      const int m = t >> 2, kk = (t & 3) * 8;
      const float* src = A + (size_t)(row0 + m) * lda + (k0 + kk);
#pragma unroll
      for (int u = 0; u < 8; ++u)
        As[m][kk + u] = (k0 + kk + u < Kreal) ? src[u] : 0.0f;
    }
    {
      const int kk = t >> 3, c = (t & 7) * 8;
      const int kg = k0 + kk;
      const float* src = W + (size_t)kg * ldb + (col0 + c);
      const bool ok = (kg < Kreal);
#pragma unroll
      for (int u = 0; u < 8; ++u) Bs[kk][c + u] = ok ? src[u] : 0.0f;
    }
    __syncthreads();
#pragma unroll
    for (int k = 0; k < 32; ++k) {
      const float a0 = As[ty * 4 + 0][k];
      const float a1 = As[ty * 4 + 1][k];
      const float a2 = As[ty * 4 + 2][k];
      const float a3 = As[ty * 4 + 3][k];
      const float4 bv = *(const float4*)&Bs[k][tx * 4];
      acc[0][0] = fmaf(a0, bv.x, acc[0][0]);
      acc[0][1] = fmaf(a0, bv.y, acc[0][1]);
      acc[0][2] = fmaf(a0, bv.z, acc[0][2]);
      acc[0][3] = fmaf(a0, bv.w, acc[0][3]);
      acc[1][0] = fmaf(a1, bv.x, acc[1][0]);
      acc[1][1] = fmaf(a1, bv.y, acc[1][1]);
      acc[1][2] = fmaf(a1, bv.z, acc[1][2]);
      acc[1][3] = fmaf(a1, bv.w, acc[1][3]);
      acc[2][0] = fmaf(a2, bv.x, acc[2][0]);
      acc[2][1] = fmaf(a2, bv.y, acc[2][1]);
      acc[2][2] = fmaf(a2, bv.z, acc[2][2]);
      acc[2][3] = fmaf(a2, bv.w, acc[2][3]);
      acc[3][0] = fmaf(a3, bv.x, acc[3][0]);
      acc[3][1] = fmaf(a3, bv.y, acc[3][1]);
      acc[3][2] = fmaf(a3, bv.z, acc[3][2]);
      acc[3][3] = fmaf(a3, bv.w, acc[3][3]);
    }
    __syncthreads();
  }
  const float b0v = bias[col0 + tx * 4 + 0];
  const float b1v = bias[col0 + tx * 4 + 1];
  const float b2v = bias[col0 + tx * 4 + 2];
  const float b3v = bias[col0 + tx * 4 + 3];
  if (COLMAX == 0) {
#pragma unroll
    for (int i = 0; i < 4; ++i) {
      float4 v;
      v.x = acc[i][0] + b0v;
      v.y = acc[i][1] + b1v;
      v.z = acc[i][2] + b2v;
      v.w = acc[i][3] + b3v;
      if (DO_RELU) {
        v.x = fmaxf(v.x, 0.0f); v.y = fmaxf(v.y, 0.0f);
        v.z = fmaxf(v.z, 0.0f); v.w = fmaxf(v.w, 0.0f);
      }
      *(float4*)&C[(size_t)(row0 + ty * 4 + i) * N + col0 + tx * 4] = v;
    }
  } else {
    const float m0 =
        fmaxf(fmaxf(acc[0][0], acc[1][0]), fmaxf(acc[2][0], acc[3][0])) + b0v;
    const float m1 =
        fmaxf(fmaxf(acc[0][1], acc[1][1]), fmaxf(acc[2][1], acc[3][1])) + b1v;
    const float m2 =
        fmaxf(fmaxf(acc[0][2], acc[1][2]), fmaxf(acc[2][2], acc[3][2])) + b2v;
    const float m3 =
        fmaxf(fmaxf(acc[0][3], acc[1][3]), fmaxf(acc[2][3], acc[3][3])) + b3v;
    red[ty][tx * 4 + 0] = m0;
    red[ty][tx * 4 + 1] = m1;
    red[ty][tx * 4 + 2] = m2;
    red[ty][tx * 4 + 3] = m3;
    __syncthreads();
    if (t < 64) {
      float mm = red[0][t];
#pragma unroll
      for (int r = 1; r < 16; ++r) mm = fmaxf(mm, red[r][t]);
      C[(size_t)(row0 >> 6) * N + col0 + t] = mm;
    }
  }
}

// ---------------- fused z-max + zW = z @ Wd0a[:512,:] (r13 WIN) -------------
__global__ __launch_bounds__(1024) void zwfused_kernel(
    const float* __restrict__ pmax, const float* __restrict__ Wd0a,
    float* __restrict__ outz, float* __restrict__ zW) {
  const int b = blockIdx.x;
  const int t = threadIdx.x;
  __shared__ float zs[512];
  __shared__ float part[4][256];
  if (t < 512) {
    float m = pmax[(size_t)(b * 16) * 512 + t];
#pragma unroll
    for (int rt = 1; rt < 16; ++rt)
      m = fmaxf(m, pmax[(size_t)(b * 16 + rt) * 512 + t]);
    zs[t] = m;
    outz[b * 512 + t] = m;
  }
  __syncthreads();
  const int c = t & 255;
  const int ch = t >> 8;
  const int q0 = ch * 128;
  float acc = 0.0f;
  for (int q = 0; q < 128; q += 4) {
    acc = fmaf(zs[q0 + q + 0], Wd0a[(q0 + q + 0) * 256 + c], acc);
    acc = fmaf(zs[q0 + q + 1], Wd0a[(q0 + q + 1) * 256 + c], acc);
    acc = fmaf(zs[q0 + q + 2], Wd0a[(q0 + q + 2) * 256 + c], acc);
    acc = fmaf(zs[q0 + q + 3], Wd0a[(q0 + q + 3) * 256 + c], acc);
  }
  part[ch][c] = acc;
  __syncthreads();
  if (t < 256)
    zW[b * 256 + t] =
        (part[0][t] + part[1][t]) + (part[2][t] + part[3][t]);
}

// ---------------- decoder 0: hd0 -> fdec, relp0(out1) -----------------------
__global__ __launch_bounds__(256) void dec0_kernel(
    const float* __restrict__ zW, const float* __restrict__ grid0,
    const float* __restrict__ Wd0a, const float* __restrict__ bd0a,
    const float* __restrict__ Wf0, const float* __restrict__ Wp0,
    float* __restrict__ fdec, float* __restrict__ out_out1) {
  const int blk = blockIdx.x;
  const int b = blk >> 5;
  const int m0 = (blk & 31) * 32;
  __shared__ __align__(16) float hd0s[32][256];
  __shared__ float g0s[32][2];
  __shared__ float wp0s[768];
  const int t = threadIdx.x;
  if (t < 64) {
    const int r = t >> 1, cc = t & 1;
    g0s[r][cc] = grid0[(m0 + r) * 2 + cc];
  }
  wp0s[t] = Wp0[t];
  wp0s[256 + t] = Wp0[256 + t];
  wp0s[512 + t] = Wp0[512 + t];
  __syncthreads();
  {
    const int c = t;
    const float w0 = Wd0a[512 * 256 + c];
    const float w1 = Wd0a[513 * 256 + c];
    const float basev = zW[b * 256 + c] + bd0a[c];
#pragma unroll 8
    for (int r = 0; r < 32; ++r) {
      const float h = fmaf(g0s[r][0], w0, fmaf(g0s[r][1], w1, basev));
      hd0s[r][c] = fmaxf(h, 0.0f);
    }
  }
  __syncthreads();
  {
    const int c = t & 127;
    const int rh = (t >> 7) * 16;
    float acc[16];
#pragma unroll
    for (int r = 0; r < 16; ++r) acc[r] = 0.0f;
    for (int q = 0; q < 256; q += 4) {
      const float w0 = Wf0[(q + 0) * 128 + c];
      const float w1 = Wf0[(q + 1) * 128 + c];
      const float w2 = Wf0[(q + 2) * 128 + c];
      const float w3 = Wf0[(q + 3) * 128 + c];
#pragma unroll
      for (int r = 0; r < 16; ++r) {
        const float4 h = *(const float4*)&hd0s[rh + r][q];
        acc[r] = fmaf(h.x, w0, fmaf(h.y, w1, fmaf(h.z, w2, fmaf(h.w, w3, acc[r]))));
      }
    }
    const size_t g0i = ((size_t)(b * M1 + m0 + rh)) * 128 + c;
#pragma unroll
    for (int r = 0; r < 16; ++r) fdec[g0i + (size_t)r * 128] = acc[r];
  }
  if (t < 96) {
    const int m = t / 3;
    const int c = t - m * 3;
    float acc = 0.0f;
    for (int q = 0; q < 256; ++q) acc = fmaf(hd0s[m][q], wp0s[q * 3 + c], acc);
    out_out1[((size_t)(b * M1 + m0 + m)) * 3 + c] = acc * 0.5f;
  }
}

// ---------------- decoder 1: per-anchor folding MLP -> out0 -----------------
__global__ __launch_bounds__(256) void dec1_kernel(
    const float* __restrict__ fdec, const float* __restrict__ grid1,
    const float* __restrict__ Wd1a, const float* __restrict__ bd1a,
    const float* __restrict__ Wp1, const float* __restrict__ out1r,
    float* __restrict__ out0w) {
  const int a0 = blockIdx.x * 16;
  __shared__ __align__(16) float fds[16][128];
  __shared__ __align__(16) float gs[16][128];
  __shared__ __align__(16) float us[16][128];
  __shared__ __align__(16) float wp1t[3][128];
  __shared__ float o1s[16][3];
  const int t = threadIdx.x;
  {
    const int r = t >> 4;
    const int c0 = (t & 15) * 8;
    const float* src = fdec + ((size_t)(a0 + r)) * 128 + c0;
#pragma unroll
    for (int u = 0; u < 8; ++u) fds[r][c0 + u] = src[u];
  }
  {
    const int k = t >> 4;
    const int c0 = (t & 15) * 8;
    const float g0 = grid1[k * 2 + 0];
    const float g1 = grid1[k * 2 + 1];
#pragma unroll
    for (int u = 0; u < 8; ++u) {
      const int c = c0 + u;
      gs[k][c] = fmaf(g0, Wd1a[128 * 128 + c], fmaf(g1, Wd1a[129 * 128 + c], bd1a[c]));
    }
  }
  if (t < 128) {
    wp1t[0][t] = Wp1[t * 3 + 0];
    wp1t[1][t] = Wp1[t * 3 + 1];
    wp1t[2][t] = Wp1[t * 3 + 2];
  }
  if (t < 48) {
    const int r = t / 3, c = t - r * 3;
    o1s[r][c] = out1r[((size_t)(a0 + r)) * 3 + c];
  }
  __syncthreads();
  {
    const int c = t & 127;
    const int mh = (t >> 7) * 8;
    float acc[8];
#pragma unroll
    for (int r = 0; r < 8; ++r) acc[r] = 0.0f;
    for (int q = 0; q < 128; q += 4) {
      const float w0 = Wd1a[(q + 0) * 128 + c];
      const float w1 = Wd1a[(q + 1) * 128 + c];
      const float w2 = Wd1a[(q + 2) * 128 + c];
      const float w3 = Wd1a[(q + 3) * 128 + c];
#pragma unroll
      for (int r = 0; r < 8; ++r) {
        const float4 f = *(const float4*)&fds[mh + r][q];
        acc[r] = fmaf(f.x, w0, fmaf(f.y, w1, fmaf(f.z, w2, fmaf(f.w, w3, acc[r]))));
      }
    }
#pragma unroll
    for (int r = 0; r < 8; ++r) us[mh + r][c] = acc[r];
  }
  __syncthreads();
  {
    const int m = t >> 4, k = t & 15;
    float a0v = 0.0f, a1v = 0.0f, a2v = 0.0f;
    for (int c = 0; c < 128; c += 4) {
      const float4 uu = *(const float4*)&us[m][c];
      const float4 gg = *(const float4*)&gs[k][c];
      const float h0 = fmaxf(uu.x + gg.x, 0.0f);
      const float h1 = fmaxf(uu.y + gg.y, 0.0f);
      const float h2 = fmaxf(uu.z + gg.z, 0.0f);
      const float h3 = fmaxf(uu.w + gg.w, 0.0f);
      const float4 wx = *(const float4*)&wp1t[0][c];
      const float4 wy = *(const float4*)&wp1t[1][c];
      const float4 wz = *(const float4*)&wp1t[2][c];
      a0v = fmaf(h0, wx.x, fmaf(h1, wx.y, fmaf(h2, wx.z, fmaf(h3, wx.w, a0v))));
      a1v = fmaf(h0, wy.x, fmaf(h1, wy.y, fmaf(h2, wy.z, fmaf(h3, wy.w, a1v))));
      a2v = fmaf(h0, wz.x, fmaf(h1, wz.y, fmaf(h2, wz.z, fmaf(h3, wz.w, a2v))));
    }
    const size_t o = (((size_t)(a0 + m)) * 16 + k) * 3;
    out0w[o + 0] = o1s[m][0] + a0v * 0.2f;
    out0w[o + 1] = o1s[m][1] + a1v * 0.2f;
    out0w[o + 2] = o1s[m][2] + a2v * 0.2f;
  }
}

extern "C" void kernel_launch(void* const* d_in, const int* in_sizes, int n_in,
                              void* d_out_v, int out_size, void* d_ws,
                              size_t ws_size, hipStream_t stream) {
  (void)in_sizes; (void)n_in; (void)out_size; (void)ws_size;
  const float* points = (const float*)d_in[0];
  const float* W0a = (const float*)d_in[1];
  const float* b0a = (const float*)d_in[2];
  const float* W0b = (const float*)d_in[3];
  const float* b0b = (const float*)d_in[4];
  const float* W1a = (const float*)d_in[5];
  const float* b1a = (const float*)d_in[6];
  const float* W1b = (const float*)d_in[7];
  const float* b1b = (const float*)d_in[8];
  const float* grid0 = (const float*)d_in[9];
  const float* Wd0a = (const float*)d_in[10];
  const float* bd0a = (const float*)d_in[11];
  const float* Wp0 = (const float*)d_in[12];
  const float* Wf0 = (const float*)d_in[13];
  const float* grid1 = (const float*)d_in[14];
  const float* Wd1a = (const float*)d_in[15];
  const float* bd1a = (const float*)d_in[16];
  const float* Wp1 = (const float*)d_in[17];
  float* out = (float*)d_out_v;
  char* ws = (char*)d_ws;

  int* fidx = (int*)(ws + 0);
  int* knn_i = (int*)(ws + 32768);
  float* knn_d = (float*)(ws + 557056);
  float* p1 = (float*)(ws + 1081344);
  float* f0 = (float*)(ws + 1179648);
  float* X1 = (float*)(ws + 5373952);
  float* mid1 = (float*)(ws + 9699328);
  int* perm = (int*)(ws + 12000000);      // overlaps mid1; consumed before
  float* pmax = (float*)(ws + 18087936);  // mid1 is written (sequential-safe)
  float* zW = (float*)(ws + 18366464);
  float* fdec = (float*)(ws + 18374656);

  sort_kernel<<<NB, 1024, 0, stream>>>(points, perm);
  fps_kernel<<<NB, 1024, 0, stream>>>(points, perm, fidx);
  gather_p1_kernel<<<(NA * 3 + 255) / 256, 256, 0, stream>>>(points, fidx, p1,
                                                             out + OUT_IP1);
  knn_kernel<<<NA / 4, 256, 0, stream>>>(points, p1, knn_i, knn_d,
                                         out + OUT_IP0);
  enc0_kernel<<<NA, 128, 0, stream>>>(out + OUT_IP0, knn_d, p1, W0a, b0a, W0b,
                                      b0b, f0);
  build_x1_kernel<<<(NA * 132 + 255) / 256, 256, 0, stream>>>(p1, f0, X1);
  gemm64_kernel<1, 0><<<dim3(4, 128), 256, 0, stream>>>(X1, W1a, b1a, mid1,
                                                        256, 132, 131, 132, 256);
  gemm64_kernel<0, 1><<<dim3(8, 128), 256, 0, stream>>>(mid1, W1b, b1b, pmax,
                                                        512, 256, 256, 256, 512);
  zwfused_kernel<<<NB, 1024, 0, stream>>>(pmax, Wd0a, out + OUT_Z, zW);
  dec0_kernel<<<256, 256, 0, stream>>>(zW, grid0, Wd0a, bd0a, Wf0, Wp0, fdec,
                                       out + OUT_OUT1);
  dec1_kernel<<<NA / 16, 256, 0, stream>>>(fdec, grid1, Wd1a, bd1a, Wp1,
                                           out + OUT_OUT1, out + OUT_OUT0);
}

// Round 17
// 3042.058 us; speedup vs baseline: 1.0003x; 1.0003x over previous
//
#include <hip/hip_runtime.h>

#define NB 8
#define NPTS 16384
#define M1 1024
#define NA 8192

// d_out float offsets
#define OUT_IP0  0
#define OUT_IP1  393216
#define OUT_OUT0 417792
#define OUT_OUT1 811008
#define OUT_Z    835584

typedef unsigned long long u64;

__device__ __forceinline__ float exact_d2(float ax, float ay, float az,
                                          float bx, float by, float bz) {
  float dx = __fsub_rn(ax, bx);
  float dy = __fsub_rn(ay, by);
  float dz = __fsub_rn(az, bz);
  return __fadd_rn(__fadd_rn(__fmul_rn(dx, dx), __fmul_rn(dy, dy)),
                   __fmul_rn(dz, dz));
}

__device__ __forceinline__ bool dl_lt(float d1, int i1, float d2, int i2) {
  return (d1 < d2) || ((d1 == d2) && (i1 < i2));
}

// DPP fmin step: old=SELF, bound_ctrl=0 -> OOB lanes combine self (no-op).
template <int CTRL>
__device__ __forceinline__ float dpp_fmin_self(float v) {
  const int s = __builtin_amdgcn_update_dpp(__float_as_int(v),
                                            __float_as_int(v), CTRL, 0xf, 0xf,
                                            false);
  return fminf(v, __int_as_float(s));
}

// DPP u64-min step (old=self).
template <int CTRL>
__device__ __forceinline__ u64 dpp_min_u64(u64 v) {
  const int lo = (int)(unsigned)v;
  const int hi = (int)(unsigned)(v >> 32);
  const int slo = __builtin_amdgcn_update_dpp(lo, lo, CTRL, 0xf, 0xf, false);
  const int shi = __builtin_amdgcn_update_dpp(hi, hi, CTRL, 0xf, 0xf, false);
  const u64 s = ((u64)(unsigned)shi << 32) | (unsigned)slo;
  return s < v ? s : v;
}

// DPP u64-max step (old=self).
template <int CTRL>
__device__ __forceinline__ u64 dpp_max_u64(u64 v) {
  const int lo = (int)(unsigned)v;
  const int hi = (int)(unsigned)(v >> 32);
  const int slo = __builtin_amdgcn_update_dpp(lo, lo, CTRL, 0xf, 0xf, false);
  const int shi = __builtin_amdgcn_update_dpp(hi, hi, CTRL, 0xf, 0xf, false);
  const u64 s = ((u64)(unsigned)shi << 32) | (unsigned)slo;
  return s > v ? s : v;
}

// ---------------- counting sort: spatial 16^3 bucketing per cloud -----------
// Scatter order within a bucket is atomic-order-dependent (nondeterministic)
// but harmless: fps selections depend only on exact per-point keys, so the
// OUTPUT is deterministic. Bucketing quality only affects skip rate.
__global__ __launch_bounds__(1024) void sort_kernel(
    const float* __restrict__ pts, int* __restrict__ perm) {
  const int b = blockIdx.x;
  const float* __restrict__ P = pts + (size_t)b * NPTS * 3;
  const int t = threadIdx.x;
  __shared__ int hist[4096];
  __shared__ int csum[64];
  for (int i = t; i < 4096; i += 1024) hist[i] = 0;
  __syncthreads();
  int cell[16];
#pragma unroll
  for (int j = 0; j < 16; ++j) {
    const int idx = t * 16 + j;
    const float x = P[idx * 3 + 0];
    const float y = P[idx * 3 + 1];
    const float z = P[idx * 3 + 2];
    int cx = (int)((x + 4.0f) * 2.0f); cx = cx < 0 ? 0 : (cx > 15 ? 15 : cx);
    int cy = (int)((y + 4.0f) * 2.0f); cy = cy < 0 ? 0 : (cy > 15 ? 15 : cy);
    int cz = (int)((z + 4.0f) * 2.0f); cz = cz < 0 ? 0 : (cz > 15 ? 15 : cz);
    const int c = (cx << 8) | (cy << 4) | cz;
    cell[j] = c;
    atomicAdd(&hist[c], 1);
  }
  __syncthreads();
  if (t < 64) {
    int s = 0;
    for (int i = 0; i < 64; ++i) s += hist[t * 64 + i];
    csum[t] = s;
  }
  __syncthreads();
  if (t == 0) {
    int run = 0;
    for (int i = 0; i < 64; ++i) { const int v = csum[i]; csum[i] = run; run += v; }
  }
  __syncthreads();
  if (t < 64) {
    int run = csum[t];
    for (int i = 0; i < 64; ++i) { const int v = hist[t * 64 + i]; hist[t * 64 + i] = run; run += v; }
  }
  __syncthreads();
#pragma unroll
  for (int j = 0; j < 16; ++j) {
    const int pos = atomicAdd(&hist[cell[j]], 1);
    perm[b * NPTS + pos] = t * 16 + j;
  }
}

// ---------------- FPS v12b: spatial chunks + provably-exact skip ------------
// r15 crash root cause: readlane(v,63) was INSIDE if(lane==0); compiler may
// sink the DPP chain into the divergent region -> lane63's copy of v never
// written -> readlane returns garbage -> wi garbage -> OOB fault. Fix:
// readlanes hoisted to convergent code (only atomicMax stays divergent);
// plus defensive wi &= NPTS-1 (no-op when correct, absmax-diagnosable if not).
// Skip bound: (dist(m,c)*0.995 - r)^2 * 0.98 >= bv with r = 1.01*max dist to
// chunk mean -> margins (~2.5%) dwarf fp error -> skip implies no dd change
// -> selections BIT-IDENTICAL. Owner of winner never skips (dist(m,c) <= r).
__global__ __launch_bounds__(1024) void fps_kernel(
    const float* __restrict__ pts, const int* __restrict__ perm,
    int* __restrict__ fidx) {
  const int b = blockIdx.x;
  const float* __restrict__ P = pts + (size_t)b * NPTS * 3;
  const int t = threadIdx.x;
  const int lane = t & 63;

  __shared__ u64 s_slot[3];
  __shared__ char s_pad[81920];  // occupancy governor (v10 best config)
  if ((int)blockIdx.x == -1) ((volatile char*)s_pad)[0] = 1;

  float px[16], py[16], pz[16], dd[16];
  int oi[16];
  const float sx = P[0], sy = P[1], sz = P[2];
  u64 kb = 0;
  float mx = 0.0f, my = 0.0f, mz = 0.0f;
#pragma unroll
  for (int j = 0; j < 16; ++j) {
    const int o = perm[b * NPTS + t * 16 + j];
    oi[j] = o;
    const float x = P[o * 3 + 0];
    const float y = P[o * 3 + 1];
    const float z = P[o * 3 + 2];
    px[j] = x; py[j] = y; pz[j] = z;
    mx += x; my += y; mz += z;
    const float d = exact_d2(x, y, z, sx, sy, sz);
    dd[j] = d;
    const u64 k = ((u64)__float_as_uint(d) << 32) | (u64)(~(unsigned)o);
    if (k > kb) kb = k;
  }
  mx *= 0.0625f; my *= 0.0625f; mz *= 0.0625f;
  float r2m = 0.0f;
#pragma unroll
  for (int j = 0; j < 16; ++j) {
    const float dx = px[j] - mx, dy = py[j] - my, dz = pz[j] - mz;
    const float r2 = fmaf(dx, dx, fmaf(dy, dy, dz * dz));
    r2m = fmaxf(r2m, r2);
  }
  const float r = sqrtf(r2m) * 1.01f;  // safe UPPER bound on max dist(p_j, m)

  if (t == 0) {
    fidx[b * M1 + 0] = 0;
    s_slot[0] = 0; s_slot[1] = 0; s_slot[2] = 0;
  }
  __syncthreads();

  for (int it = 1; it < M1; ++it) {
    const int par = it % 3;
    const int nxt = (it + 1) % 3;
    // ---- wave reduce on u64 key (DPP, exact ties); ALL CONVERGENT ----
    u64 v = kb;
    v = dpp_max_u64<0x111>(v);
    v = dpp_max_u64<0x112>(v);
    v = dpp_max_u64<0x114>(v);
    v = dpp_max_u64<0x118>(v);
    v = dpp_max_u64<0x142>(v);
    v = dpp_max_u64<0x143>(v);
    // readlanes in convergent code (r15 fix)
    const unsigned wlo =
        (unsigned)__builtin_amdgcn_readlane((int)(unsigned)v, 63);
    const unsigned whi =
        (unsigned)__builtin_amdgcn_readlane((int)(unsigned)(v >> 32), 63);
    if (lane == 0) atomicMax(&s_slot[par], ((u64)whi << 32) | wlo);
    if (t == 0) s_slot[nxt] = 0;
    __syncthreads();
    const u64 g = s_slot[par];
    const int wi =
        __builtin_amdgcn_readfirstlane((int)(~(unsigned)g)) & (NPTS - 1);
    if (t == 0) fidx[b * M1 + it] = wi;
    const float cx = P[wi * 3 + 0];  // uniform -> scalar loads
    const float cy = P[wi * 3 + 1];
    const float cz = P[wi * 3 + 2];
    // ---- conservative skip bound ----
    const float bvf = __uint_as_float((unsigned)(kb >> 32));
    const float ex = mx - cx, ey = my - cy, ez = mz - cz;
    const float d2mc = fmaf(ex, ex, fmaf(ey, ey, ez * ez));
    const float s = sqrtf(d2mc);
    const float lb = fmaf(s, 0.995f, -r);  // safe LOWER bound on dist(p_j,c)
    const bool skip = (lb > 0.0f) && (lb * lb * 0.98f >= bvf);
    if (!skip) {
      kb = 0;
#pragma unroll
      for (int j = 0; j < 16; ++j) {
        const float d2 = exact_d2(px[j], py[j], pz[j], cx, cy, cz);
        const float nd = fminf(dd[j], d2);
        dd[j] = nd;
        const u64 k =
            ((u64)__float_as_uint(nd) << 32) | (u64)(~(unsigned)oi[j]);
        if (k > kb) kb = k;
      }
    }
  }
}

// ---------------- gather p1 (also output ip1) -------------------------------
__global__ void gather_p1_kernel(const float* __restrict__ pts,
                                 const int* __restrict__ fidx,
                                 float* __restrict__ p1,
                                 float* __restrict__ out_ip1) {
  const int i = blockIdx.x * 256 + threadIdx.x;
  if (i >= NA * 3) return;
  const int a = i / 3, c = i - a * 3;
  const int b = a >> 10;
  const int src = fidx[a];
  const float v = pts[((size_t)b * NPTS + src) * 3 + c];
  p1[i] = v;
  out_ip1[i] = v;
}

// ---------------- KNN v2: DPP everywhere (r13 WIN) --------------------------
__global__ __launch_bounds__(256) void knn_kernel(
    const float* __restrict__ pts, const float* __restrict__ p1,
    int* __restrict__ knn_i, float* __restrict__ knn_d,
    float* __restrict__ out_ip0) {
  const int wq = threadIdx.x >> 6;
  const int lane = threadIdx.x & 63;
  const int a = blockIdx.x * 4 + wq;
  const int b = a >> 10;
  const float* __restrict__ P = pts + (size_t)b * NPTS * 3;
  const float qx = p1[a * 3 + 0], qy = p1[a * 3 + 1], qz = p1[a * 3 + 2];
  const float INF = __builtin_inff();
  float D[16]; int I[16];
#pragma unroll
  for (int s = 0; s < 16; ++s) { D[s] = INF; I[s] = 0x7fffffff; }
  float wstar = INF;

  for (int s = 0; s < NPTS / 64; ++s) {
    const int idx = s * 64 + lane;
    const float x = P[idx * 3 + 0];
    const float y = P[idx * 3 + 1];
    const float z = P[idx * 3 + 2];
    const float d2 = exact_d2(x, y, z, qx, qy, qz);
    const bool pass = (d2 <= wstar);
    if (__any(pass)) {
      if (pass && dl_lt(d2, idx, D[15], I[15])) {
        bool c[16];
#pragma unroll
        for (int u = 0; u < 16; ++u) c[u] = dl_lt(d2, idx, D[u], I[u]);
#pragma unroll
        for (int u = 15; u >= 1; --u) {
          D[u] = c[u] ? (c[u - 1] ? D[u - 1] : d2) : D[u];
          I[u] = c[u] ? (c[u - 1] ? I[u - 1] : idx) : I[u];
        }
        if (c[0]) { D[0] = d2; I[0] = idx; }
      }
      float w = D[15];
      w = dpp_fmin_self<0x111>(w);
      w = dpp_fmin_self<0x112>(w);
      w = dpp_fmin_self<0x114>(w);
      w = dpp_fmin_self<0x118>(w);
      w = dpp_fmin_self<0x142>(w);
      w = dpp_fmin_self<0x143>(w);
      wstar = __int_as_float(
          __builtin_amdgcn_readlane(__float_as_int(w), 63));
    }
  }

  __shared__ u64 sk[4][1024];
#pragma unroll
  for (int u = 0; u < 16; ++u)
    sk[wq][lane * 16 + u] =
        ((u64)__float_as_uint(D[u]) << 32) | (unsigned)I[u];
  int head = lane * 16;
  const int hend = head + 16;
  u64 md = sk[wq][head];
  u64 outK = 0;
  for (int r = 0; r < 16; ++r) {
    u64 v = md;
    v = dpp_min_u64<0x111>(v);
    v = dpp_min_u64<0x112>(v);
    v = dpp_min_u64<0x114>(v);
    v = dpp_min_u64<0x118>(v);
    v = dpp_min_u64<0x142>(v);
    v = dpp_min_u64<0x143>(v);
    const unsigned glo =
        (unsigned)__builtin_amdgcn_readlane((int)(unsigned)v, 63);
    const unsigned ghi =
        (unsigned)__builtin_amdgcn_readlane((int)(unsigned)(v >> 32), 63);
    const u64 g = ((u64)ghi << 32) | glo;
    if (lane == r) outK = g;
    if (md == g) {
      ++head;
      md = (head < hend) ? sk[wq][head] : ~0ull;
    }
  }
  if (lane < 16) {
    const int o = a * 16 + lane;
    const int outI = (int)(unsigned)outK;
    knn_i[o] = outI;
    knn_d[o] = __uint_as_float((unsigned)(outK >> 32));
    out_ip0[(size_t)o * 3 + 0] = P[outI * 3 + 0];
    out_ip0[(size_t)o * 3 + 1] = P[outI * 3 + 1];
    out_ip0[(size_t)o * 3 + 2] = P[outI * 3 + 2];
  }
}

// ---------------- encoder 0: per-anchor shared MLP + max pool ---------------
__global__ __launch_bounds__(128) void enc0_kernel(
    const float* __restrict__ ip0, const float* __restrict__ knn_d,
    const float* __restrict__ p1, const float* __restrict__ W0a,
    const float* __restrict__ b0a, const float* __restrict__ W0b,
    const float* __restrict__ b0b, float* __restrict__ f0) {
  const int a = blockIdx.x;
  __shared__ float rel[16][4];
  __shared__ __align__(16) float h1s[16][64];
  const int t = threadIdx.x;
  if (t < 16) {
    const float ax = p1[a * 3 + 0], ay = p1[a * 3 + 1], az = p1[a * 3 + 2];
    const float kd = knn_d[a * 16 + t];
    const bool within = (kd <= 0.04f);
    const float* nb = ip0 + (size_t)(a * 16 + t) * 3;
    rel[t][0] = within ? (nb[0] - ax) * 5.0f : 0.0f;
    rel[t][1] = within ? (nb[1] - ay) * 5.0f : 0.0f;
    rel[t][2] = within ? (nb[2] - az) * 5.0f : 0.0f;
  }
  __syncthreads();
  {
    const int m = t & 63, kh = t >> 6;
    const float w0 = W0a[m], w1 = W0a[64 + m], w2 = W0a[128 + m];
    const float bb = b0a[m];
#pragma unroll
    for (int kk = 0; kk < 8; ++kk) {
      const int k = kh * 8 + kk;
      const float h =
          fmaf(rel[k][0], w0, fmaf(rel[k][1], w1, fmaf(rel[k][2], w2, bb)));
      h1s[k][m] = fmaxf(h, 0.0f);
    }
  }
  __syncthreads();
  {
    const int col = t;  // 0..127
    float acc[16];
#pragma unroll
    for (int k = 0; k < 16; ++k) acc[k] = 0.0f;
    for (int m = 0; m < 64; m += 4) {
      const float w0 = W0b[(m + 0) * 128 + col];
      const float w1 = W0b[(m + 1) * 128 + col];
      const float w2 = W0b[(m + 2) * 128 + col];
      const float w3 = W0b[(m + 3) * 128 + col];
#pragma unroll
      for (int k = 0; k < 16; ++k) {
        const float4 h = *(const float4*)&h1s[k][m];
        acc[k] = fmaf(h.x, w0, fmaf(h.y, w1, fmaf(h.z, w2, fmaf(h.w, w3, acc[k]))));
      }
    }
    float mx = acc[0];
#pragma unroll
    for (int k = 1; k < 16; ++k) mx = fmaxf(mx, acc[k]);
    f0[(size_t)a * 128 + col] = mx + b0b[col];
  }
}

// ---------------- build X1 = [p1*2 | f0 | 0pad] ------------------------------
__global__ void build_x1_kernel(const float* __restrict__ p1,
                                const float* __restrict__ f0,
                                float* __restrict__ X1) {
  const int i = blockIdx.x * 256 + threadIdx.x;
  if (i >= NA * 132) return;
  const int r = i / 132, c = i - r * 132;
  float v;
  if (c < 3) v = p1[r * 3 + c] * 2.0f;
  else if (c < 131) v = f0[(size_t)r * 128 + (c - 3)];
  else v = 0.0f;
  X1[i] = v;
}

// ---------------- generic 64x64 fp32 GEMM (+bias, optional relu/colmax) -----
template <int DO_RELU, int COLMAX>
__global__ __launch_bounds__(256) void gemm64_kernel(
    const float* __restrict__ A, const float* __restrict__ W,
    const float* __restrict__ bias, float* __restrict__ C, const int N,
    const int K, const int Kreal, const int lda, const int ldb) {
  __shared__ float As[64][33];
  __shared__ __align__(16) float Bs[32][64];
  __shared__ float red[16][64];
  const int t = threadIdx.x;
  const int tx = t & 15, ty = t >> 4;
  const int row0 = blockIdx.y * 64, col0 = blockIdx.x * 64;
  float acc[4][4] = {};
  for (int k0 = 0; k0 < K; k0 += 32) {
    {
      const int m = t >> 2, kk = (t & 3) * 8;
      const float* src = A + (size_t)(row0 + m) * lda + (k0 + kk);
#pragma unroll
      for (int u = 0; u < 8; ++u)
        As[m][kk + u] = (k0 + kk + u < Kreal) ? src[u] : 0.0f;
    }
    {
      const int kk = t >> 3, c = (t & 7) * 8;
      const int kg = k0 + kk;
      const float* src = W + (size_t)kg * ldb + (col0 + c);
      const bool ok = (kg < Kreal);
#pragma unroll
      for (int u = 0; u < 8; ++u) Bs[kk][c + u] = ok ? src[u] : 0.0f;
    }
    __syncthreads();
#pragma unroll
    for (int k = 0; k < 32; ++k) {
      const float a0 = As[ty * 4 + 0][k];
      const float a1 = As[ty * 4 + 1][k];
      const float a2 = As[ty * 4 + 2][k];
      const float a3 = As[ty * 4 + 3][k];
      const float4 bv = *(const float4*)&Bs[k][tx * 4];
      acc[0][0] = fmaf(a0, bv.x, acc[0][0]);
      acc[0][1] = fmaf(a0, bv.y, acc[0][1]);
      acc[0][2] = fmaf(a0, bv.z, acc[0][2]);
      acc[0][3] = fmaf(a0, bv.w, acc[0][3]);
      acc[1][0] = fmaf(a1, bv.x, acc[1][0]);
      acc[1][1] = fmaf(a1, bv.y, acc[1][1]);
      acc[1][2] = fmaf(a1, bv.z, acc[1][2]);
      acc[1][3] = fmaf(a1, bv.w, acc[1][3]);
      acc[2][0] = fmaf(a2, bv.x, acc[2][0]);
      acc[2][1] = fmaf(a2, bv.y, acc[2][1]);
      acc[2][2] = fmaf(a2, bv.z, acc[2][2]);
      acc[2][3] = fmaf(a2, bv.w, acc[2][3]);
      acc[3][0] = fmaf(a3, bv.x, acc[3][0]);
      acc[3][1] = fmaf(a3, bv.y, acc[3][1]);
      acc[3][2] = fmaf(a3, bv.z, acc[3][2]);
      acc[3][3] = fmaf(a3, bv.w, acc[3][3]);
    }
    __syncthreads();
  }
  const float b0v = bias[col0 + tx * 4 + 0];
  const float b1v = bias[col0 + tx * 4 + 1];
  const float b2v = bias[col0 + tx * 4 + 2];
  const float b3v = bias[col0 + tx * 4 + 3];
  if (COLMAX == 0) {
#pragma unroll
    for (int i = 0; i < 4; ++i) {
      float4 v;
      v.x = acc[i][0] + b0v;
      v.y = acc[i][1] + b1v;
      v.z = acc[i][2] + b2v;
      v.w = acc[i][3] + b3v;
      if (DO_RELU) {
        v.x = fmaxf(v.x, 0.0f); v.y = fmaxf(v.y, 0.0f);
        v.z = fmaxf(v.z, 0.0f); v.w = fmaxf(v.w, 0.0f);
      }
      *(float4*)&C[(size_t)(row0 + ty * 4 + i) * N + col0 + tx * 4] = v;
    }
  } else {
    const float m0 =
        fmaxf(fmaxf(acc[0][0], acc[1][0]), fmaxf(acc[2][0], acc[3][0])) + b0v;
    const float m1 =
        fmaxf(fmaxf(acc[0][1], acc[1][1]), fmaxf(acc[2][1], acc[3][1])) + b1v;
    const float m2 =
        fmaxf(fmaxf(acc[0][2], acc[1][2]), fmaxf(acc[2][2], acc[3][2])) + b2v;
    const float m3 =
        fmaxf(fmaxf(acc[0][3], acc[1][3]), fmaxf(acc[2][3], acc[3][3])) + b3v;
    red[ty][tx * 4 + 0] = m0;
    red[ty][tx * 4 + 1] = m1;
    red[ty][tx * 4 + 2] = m2;
    red[ty][tx * 4 + 3] = m3;
    __syncthreads();
    if (t < 64) {
      float mm = red[0][t];
#pragma unroll
      for (int r = 1; r < 16; ++r) mm = fmaxf(mm, red[r][t]);
      C[(size_t)(row0 >> 6) * N + col0 + t] = mm;
    }
  }
}

// ---------------- fused z-max + zW = z @ Wd0a[:512,:] (r13 WIN) -------------
__global__ __launch_bounds__(1024) void zwfused_kernel(
    const float* __restrict__ pmax, const float* __restrict__ Wd0a,
    float* __restrict__ outz, float* __restrict__ zW) {
  const int b = blockIdx.x;
  const int t = threadIdx.x;
  __shared__ float zs[512];
  __shared__ float part[4][256];
  if (t < 512) {
    float m = pmax[(size_t)(b * 16) * 512 + t];
#pragma unroll
    for (int rt = 1; rt < 16; ++rt)
      m = fmaxf(m, pmax[(size_t)(b * 16 + rt) * 512 + t]);
    zs[t] = m;
    outz[b * 512 + t] = m;
  }
  __syncthreads();
  const int c = t & 255;
  const int ch = t >> 8;
  const int q0 = ch * 128;
  float acc = 0.0f;
  for (int q = 0; q < 128; q += 4) {
    acc = fmaf(zs[q0 + q + 0], Wd0a[(q0 + q + 0) * 256 + c], acc);
    acc = fmaf(zs[q0 + q + 1], Wd0a[(q0 + q + 1) * 256 + c], acc);
    acc = fmaf(zs[q0 + q + 2], Wd0a[(q0 + q + 2) * 256 + c], acc);
    acc = fmaf(zs[q0 + q + 3], Wd0a[(q0 + q + 3) * 256 + c], acc);
  }
  part[ch][c] = acc;
  __syncthreads();
  if (t < 256)
    zW[b * 256 + t] =
        (part[0][t] + part[1][t]) + (part[2][t] + part[3][t]);
}

// ---------------- decoder 0: hd0 -> fdec, relp0(out1) -----------------------
__global__ __launch_bounds__(256) void dec0_kernel(
    const float* __restrict__ zW, const float* __restrict__ grid0,
    const float* __restrict__ Wd0a, const float* __restrict__ bd0a,
    const float* __restrict__ Wf0, const float* __restrict__ Wp0,
    float* __restrict__ fdec, float* __restrict__ out_out1) {
  const int blk = blockIdx.x;
  const int b = blk >> 5;
  const int m0 = (blk & 31) * 32;
  __shared__ __align__(16) float hd0s[32][256];
  __shared__ float g0s[32][2];
  __shared__ float wp0s[768];
  const int t = threadIdx.x;
  if (t < 64) {
    const int r = t >> 1, cc = t & 1;
    g0s[r][cc] = grid0[(m0 + r) * 2 + cc];
  }
  wp0s[t] = Wp0[t];
  wp0s[256 + t] = Wp0[256 + t];
  wp0s[512 + t] = Wp0[512 + t];
  __syncthreads();
  {
    const int c = t;
    const float w0 = Wd0a[512 * 256 + c];
    const float w1 = Wd0a[513 * 256 + c];
    const float basev = zW[b * 256 + c] + bd0a[c];
#pragma unroll 8
    for (int r = 0; r < 32; ++r) {
      const float h = fmaf(g0s[r][0], w0, fmaf(g0s[r][1], w1, basev));
      hd0s[r][c] = fmaxf(h, 0.0f);
    }
  }
  __syncthreads();
  {
    const int c = t & 127;
    const int rh = (t >> 7) * 16;
    float acc[16];
#pragma unroll
    for (int r = 0; r < 16; ++r) acc[r] = 0.0f;
    for (int q = 0; q < 256; q += 4) {
      const float w0 = Wf0[(q + 0) * 128 + c];
      const float w1 = Wf0[(q + 1) * 128 + c];
      const float w2 = Wf0[(q + 2) * 128 + c];
      const float w3 = Wf0[(q + 3) * 128 + c];
#pragma unroll
      for (int r = 0; r < 16; ++r) {
        const float4 h = *(const float4*)&hd0s[rh + r][q];
        acc[r] = fmaf(h.x, w0, fmaf(h.y, w1, fmaf(h.z, w2, fmaf(h.w, w3, acc[r]))));
      }
    }
    const size_t g0i = ((size_t)(b * M1 + m0 + rh)) * 128 + c;
#pragma unroll
    for (int r = 0; r < 16; ++r) fdec[g0i + (size_t)r * 128] = acc[r];
  }
  if (t < 96) {
    const int m = t / 3;
    const int c = t - m * 3;
    float acc = 0.0f;
    for (int q = 0; q < 256; ++q) acc = fmaf(hd0s[m][q], wp0s[q * 3 + c], acc);
    out_out1[((size_t)(b * M1 + m0 + m)) * 3 + c] = acc * 0.5f;
  }
}

// ---------------- decoder 1: per-anchor folding MLP -> out0 -----------------
__global__ __launch_bounds__(256) void dec1_kernel(
    const float* __restrict__ fdec, const float* __restrict__ grid1,
    const float* __restrict__ Wd1a, const float* __restrict__ bd1a,
    const float* __restrict__ Wp1, const float* __restrict__ out1r,
    float* __restrict__ out0w) {
  const int a0 = blockIdx.x * 16;
  __shared__ __align__(16) float fds[16][128];
  __shared__ __align__(16) float gs[16][128];
  __shared__ __align__(16) float us[16][128];
  __shared__ __align__(16) float wp1t[3][128];
  __shared__ float o1s[16][3];
  const int t = threadIdx.x;
  {
    const int r = t >> 4;
    const int c0 = (t & 15) * 8;
    const float* src = fdec + ((size_t)(a0 + r)) * 128 + c0;
#pragma unroll
    for (int u = 0; u < 8; ++u) fds[r][c0 + u] = src[u];
  }
  {
    const int k = t >> 4;
    const int c0 = (t & 15) * 8;
    const float g0 = grid1[k * 2 + 0];
    const float g1 = grid1[k * 2 + 1];
#pragma unroll
    for (int u = 0; u < 8; ++u) {
      const int c = c0 + u;
      gs[k][c] = fmaf(g0, Wd1a[128 * 128 + c], fmaf(g1, Wd1a[129 * 128 + c], bd1a[c]));
    }
  }
  if (t < 128) {
    wp1t[0][t] = Wp1[t * 3 + 0];
    wp1t[1][t] = Wp1[t * 3 + 1];
    wp1t[2][t] = Wp1[t * 3 + 2];
  }
  if (t < 48) {
    const int r = t / 3, c = t - r * 3;
    o1s[r][c] = out1r[((size_t)(a0 + r)) * 3 + c];
  }
  __syncthreads();
  {
    const int c = t & 127;
    const int mh = (t >> 7) * 8;
    float acc[8];
#pragma unroll
    for (int r = 0; r < 8; ++r) acc[r] = 0.0f;
    for (int q = 0; q < 128; q += 4) {
      const float w0 = Wd1a[(q + 0) * 128 + c];
      const float w1 = Wd1a[(q + 1) * 128 + c];
      const float w2 = Wd1a[(q + 2) * 128 + c];
      const float w3 = Wd1a[(q + 3) * 128 + c];
#pragma unroll
      for (int r = 0; r < 8; ++r) {
        const float4 f = *(const float4*)&fds[mh + r][q];
        acc[r] = fmaf(f.x, w0, fmaf(f.y, w1, fmaf(f.z, w2, fmaf(f.w, w3, acc[r]))));
      }
    }
#pragma unroll
    for (int r = 0; r < 8; ++r) us[mh + r][c] = acc[r];
  }
  __syncthreads();
  {
    const int m = t >> 4, k = t & 15;
    float a0v = 0.0f, a1v = 0.0f, a2v = 0.0f;
    for (int c = 0; c < 128; c += 4) {
      const float4 uu = *(const float4*)&us[m][c];
      const float4 gg = *(const float4*)&gs[k][c];
      const float h0 = fmaxf(uu.x + gg.x, 0.0f);
      const float h1 = fmaxf(uu.y + gg.y, 0.0f);
      const float h2 = fmaxf(uu.z + gg.z, 0.0f);
      const float h3 = fmaxf(uu.w + gg.w, 0.0f);
      const float4 wx = *(const float4*)&wp1t[0][c];
      const float4 wy = *(const float4*)&wp1t[1][c];
      const float4 wz = *(const float4*)&wp1t[2][c];
      a0v = fmaf(h0, wx.x, fmaf(h1, wx.y, fmaf(h2, wx.z, fmaf(h3, wx.w, a0v))));
      a1v = fmaf(h0, wy.x, fmaf(h1, wy.y, fmaf(h2, wy.z, fmaf(h3, wy.w, a1v))));
      a2v = fmaf(h0, wz.x, fmaf(h1, wz.y, fmaf(h2, wz.z, fmaf(h3, wz.w, a2v))));
    }
    const size_t o = (((size_t)(a0 + m)) * 16 + k) * 3;
    out0w[o + 0] = o1s[m][0] + a0v * 0.2f;
    out0w[o + 1] = o1s[m][1] + a1v * 0.2f;
    out0w[o + 2] = o1s[m][2] + a2v * 0.2f;
  }
}

extern "C" void kernel_launch(void* const* d_in, const int* in_sizes, int n_in,
                              void* d_out_v, int out_size, void* d_ws,
                              size_t ws_size, hipStream_t stream) {
  (void)in_sizes; (void)n_in; (void)out_size; (void)ws_size;
  const float* points = (const float*)d_in[0];
  const float* W0a = (const float*)d_in[1];
  const float* b0a = (const float*)d_in[2];
  const float* W0b = (const float*)d_in[3];
  const float* b0b = (const float*)d_in[4];
  const float* W1a = (const float*)d_in[5];
  const float* b1a = (const float*)d_in[6];
  const float* W1b = (const float*)d_in[7];
  const float* b1b = (const float*)d_in[8];
  const float* grid0 = (const float*)d_in[9];
  const float* Wd0a = (const float*)d_in[10];
  const float* bd0a = (const float*)d_in[11];
  const float* Wp0 = (const float*)d_in[12];
  const float* Wf0 = (const float*)d_in[13];
  const float* grid1 = (const float*)d_in[14];
  const float* Wd1a = (const float*)d_in[15];
  const float* bd1a = (const float*)d_in[16];
  const float* Wp1 = (const float*)d_in[17];
  float* out = (float*)d_out_v;
  char* ws = (char*)d_ws;

  int* fidx = (int*)(ws + 0);
  int* knn_i = (int*)(ws + 32768);
  float* knn_d = (float*)(ws + 557056);
  float* p1 = (float*)(ws + 1081344);
  float* f0 = (float*)(ws + 1179648);
  float* X1 = (float*)(ws + 5373952);
  float* mid1 = (float*)(ws + 9699328);
  int* perm = (int*)(ws + 12000000);      // overlaps mid1; consumed before
  float* pmax = (float*)(ws + 18087936);  // mid1 is written (sequential-safe)
  float* zW = (float*)(ws + 18366464);
  float* fdec = (float*)(ws + 18374656);

  sort_kernel<<<NB, 1024, 0, stream>>>(points, perm);
  fps_kernel<<<NB, 1024, 0, stream>>>(points, perm, fidx);
  gather_p1_kernel<<<(NA * 3 + 255) / 256, 256, 0, stream>>>(points, fidx, p1,
                                                             out + OUT_IP1);
  knn_kernel<<<NA / 4, 256, 0, stream>>>(points, p1, knn_i, knn_d,
                                         out + OUT_IP0);
  enc0_kernel<<<NA, 128, 0, stream>>>(out + OUT_IP0, knn_d, p1, W0a, b0a, W0b,
                                      b0b, f0);
  build_x1_kernel<<<(NA * 132 + 255) / 256, 256, 0, stream>>>(p1, f0, X1);
  gemm64_kernel<1, 0><<<dim3(4, 128), 256, 0, stream>>>(X1, W1a, b1a, mid1,
                                                        256, 132, 131, 132, 256);
  gemm64_kernel<0, 1><<<dim3(8, 128), 256, 0, stream>>>(mid1, W1b, b1b, pmax,
                                                        512, 256, 256, 256, 512);
  zwfused_kernel<<<NB, 1024, 0, stream>>>(pmax, Wd0a, out + OUT_Z, zW);
  dec0_kernel<<<256, 256, 0, stream>>>(zW, grid0, Wd0a, bd0a, Wf0, Wp0, fdec,
                                       out + OUT_OUT1);
  dec1_kernel<<<NA / 16, 256, 0, stream>>>(fdec, grid1, Wd1a, bd1a, Wp1,
                                           out + OUT_OUT1, out + OUT_OUT0);
}

// Round 18
// 2702.811 us; speedup vs baseline: 1.1258x; 1.1255x over previous
//
#include <hip/hip_runtime.h>

#define NB 8
#define NPTS 16384
#define M1 1024
#define NA 8192

// d_out float offsets
#define OUT_IP0  0
#define OUT_IP1  393216
#define OUT_OUT0 417792
#define OUT_OUT1 811008
#define OUT_Z    835584

typedef unsigned long long u64;

__device__ __forceinline__ float exact_d2(float ax, float ay, float az,
                                          float bx, float by, float bz) {
  float dx = __fsub_rn(ax, bx);
  float dy = __fsub_rn(ay, by);
  float dz = __fsub_rn(az, bz);
  return __fadd_rn(__fadd_rn(__fmul_rn(dx, dx), __fmul_rn(dy, dy)),
                   __fmul_rn(dz, dz));
}

__device__ __forceinline__ bool dl_lt(float d1, int i1, float d2, int i2) {
  return (d1 < d2) || ((d1 == d2) && (i1 < i2));
}

// DPP fmin step: old=SELF, bound_ctrl=0 -> OOB lanes combine self (no-op).
template <int CTRL>
__device__ __forceinline__ float dpp_fmin_self(float v) {
  const int s = __builtin_amdgcn_update_dpp(__float_as_int(v),
                                            __float_as_int(v), CTRL, 0xf, 0xf,
                                            false);
  return fminf(v, __int_as_float(s));
}

// DPP u64-min step (old=self).
template <int CTRL>
__device__ __forceinline__ u64 dpp_min_u64(u64 v) {
  const int lo = (int)(unsigned)v;
  const int hi = (int)(unsigned)(v >> 32);
  const int slo = __builtin_amdgcn_update_dpp(lo, lo, CTRL, 0xf, 0xf, false);
  const int shi = __builtin_amdgcn_update_dpp(hi, hi, CTRL, 0xf, 0xf, false);
  const u64 s = ((u64)(unsigned)shi << 32) | (unsigned)slo;
  return s < v ? s : v;
}

// DPP u64-max step (old=self).
template <int CTRL>
__device__ __forceinline__ u64 dpp_max_u64(u64 v) {
  const int lo = (int)(unsigned)v;
  const int hi = (int)(unsigned)(v >> 32);
  const int slo = __builtin_amdgcn_update_dpp(lo, lo, CTRL, 0xf, 0xf, false);
  const int shi = __builtin_amdgcn_update_dpp(hi, hi, CTRL, 0xf, 0xf, false);
  const u64 s = ((u64)(unsigned)shi << 32) | (unsigned)slo;
  return s > v ? s : v;
}

// ---------------- counting sort: spatial 16^3 bucketing per cloud -----------
// Scatter order within a bucket is atomic-order-dependent (nondeterministic)
// but harmless: fps selections depend only on exact per-point keys, so the
// OUTPUT is deterministic. Bucketing quality only affects skip rate.
__global__ __launch_bounds__(1024) void sort_kernel(
    const float* __restrict__ pts, int* __restrict__ perm) {
  const int b = blockIdx.x;
  const float* __restrict__ P = pts + (size_t)b * NPTS * 3;
  const int t = threadIdx.x;
  __shared__ int hist[4096];
  __shared__ int csum[64];
  for (int i = t; i < 4096; i += 1024) hist[i] = 0;
  __syncthreads();
  int cell[16];
#pragma unroll
  for (int j = 0; j < 16; ++j) {
    const int idx = t * 16 + j;
    const float x = P[idx * 3 + 0];
    const float y = P[idx * 3 + 1];
    const float z = P[idx * 3 + 2];
    int cx = (int)((x + 4.0f) * 2.0f); cx = cx < 0 ? 0 : (cx > 15 ? 15 : cx);
    int cy = (int)((y + 4.0f) * 2.0f); cy = cy < 0 ? 0 : (cy > 15 ? 15 : cy);
    int cz = (int)((z + 4.0f) * 2.0f); cz = cz < 0 ? 0 : (cz > 15 ? 15 : cz);
    const int c = (cx << 8) | (cy << 4) | cz;
    cell[j] = c;
    atomicAdd(&hist[c], 1);
  }
  __syncthreads();
  if (t < 64) {
    int s = 0;
    for (int i = 0; i < 64; ++i) s += hist[t * 64 + i];
    csum[t] = s;
  }
  __syncthreads();
  if (t == 0) {
    int run = 0;
    for (int i = 0; i < 64; ++i) { const int v = csum[i]; csum[i] = run; run += v; }
  }
  __syncthreads();
  if (t < 64) {
    int run = csum[t];
    for (int i = 0; i < 64; ++i) { const int v = hist[t * 64 + i]; hist[t * 64 + i] = run; run += v; }
  }
  __syncthreads();
#pragma unroll
  for (int j = 0; j < 16; ++j) {
    const int pos = atomicAdd(&hist[cell[j]], 1);
    perm[b * NPTS + pos] = t * 16 + j;
  }
}

// ---------------- FPS v13: WAVE-granular exact skip -------------------------
// r17 regression root cause: per-thread skip is useless under SIMT — masked
// lanes still issue, so a wave paid bound-math AND the full spill-laden
// update unless all 64 lanes independently skipped (never). v13 makes the
// skip wave-uniform: if (__all(skip_lane)) -> scalar branch, whole wave
// (1024 consecutive sorted points = one spatial region) skips the update.
// __all only STRENGTHENS the per-lane proven-unchanged condition, so
// selections remain BIT-IDENTICAL. Bound margins as r16 (~2.5% >> fp eps).
__global__ __launch_bounds__(1024) void fps_kernel(
    const float* __restrict__ pts, const int* __restrict__ perm,
    int* __restrict__ fidx) {
  const int b = blockIdx.x;
  const float* __restrict__ P = pts + (size_t)b * NPTS * 3;
  const int t = threadIdx.x;
  const int lane = t & 63;

  __shared__ u64 s_slot[3];
  __shared__ char s_pad[81920];  // occupancy governor (v10 best config)
  if ((int)blockIdx.x == -1) ((volatile char*)s_pad)[0] = 1;

  float px[16], py[16], pz[16], dd[16];
  int oi[16];
  const float sx = P[0], sy = P[1], sz = P[2];
  u64 kb = 0;
  float mx = 0.0f, my = 0.0f, mz = 0.0f;
#pragma unroll
  for (int j = 0; j < 16; ++j) {
    const int o = perm[b * NPTS + t * 16 + j];
    oi[j] = o;
    const float x = P[o * 3 + 0];
    const float y = P[o * 3 + 1];
    const float z = P[o * 3 + 2];
    px[j] = x; py[j] = y; pz[j] = z;
    mx += x; my += y; mz += z;
    const float d = exact_d2(x, y, z, sx, sy, sz);
    dd[j] = d;
    const u64 k = ((u64)__float_as_uint(d) << 32) | (u64)(~(unsigned)o);
    if (k > kb) kb = k;
  }
  mx *= 0.0625f; my *= 0.0625f; mz *= 0.0625f;
  float r2m = 0.0f;
#pragma unroll
  for (int j = 0; j < 16; ++j) {
    const float dx = px[j] - mx, dy = py[j] - my, dz = pz[j] - mz;
    const float r2 = fmaf(dx, dx, fmaf(dy, dy, dz * dz));
    r2m = fmaxf(r2m, r2);
  }
  const float r = sqrtf(r2m) * 1.01f;  // safe UPPER bound on max dist(p_j, m)

  if (t == 0) {
    fidx[b * M1 + 0] = 0;
    s_slot[0] = 0; s_slot[1] = 0; s_slot[2] = 0;
  }
  __syncthreads();

  for (int it = 1; it < M1; ++it) {
    const int par = it % 3;
    const int nxt = (it + 1) % 3;
    // ---- wave reduce on u64 key (DPP, exact ties); ALL CONVERGENT ----
    u64 v = kb;
    v = dpp_max_u64<0x111>(v);
    v = dpp_max_u64<0x112>(v);
    v = dpp_max_u64<0x114>(v);
    v = dpp_max_u64<0x118>(v);
    v = dpp_max_u64<0x142>(v);
    v = dpp_max_u64<0x143>(v);
    // readlanes in convergent code (r16 fix)
    const unsigned wlo =
        (unsigned)__builtin_amdgcn_readlane((int)(unsigned)v, 63);
    const unsigned whi =
        (unsigned)__builtin_amdgcn_readlane((int)(unsigned)(v >> 32), 63);
    if (lane == 0) atomicMax(&s_slot[par], ((u64)whi << 32) | wlo);
    if (t == 0) s_slot[nxt] = 0;
    __syncthreads();
    const u64 g = s_slot[par];
    const int wi =
        __builtin_amdgcn_readfirstlane((int)(~(unsigned)g)) & (NPTS - 1);
    if (t == 0) fidx[b * M1 + it] = wi;
    const float cx = P[wi * 3 + 0];  // uniform -> scalar loads
    const float cy = P[wi * 3 + 1];
    const float cz = P[wi * 3 + 2];
    // ---- conservative skip bound, WAVE-granular ----
    const float bvf = __uint_as_float((unsigned)(kb >> 32));
    const float ex = mx - cx, ey = my - cy, ez = mz - cz;
    const float d2mc = fmaf(ex, ex, fmaf(ey, ey, ez * ez));
    const float s = sqrtf(d2mc);
    const float lb = fmaf(s, 0.995f, -r);  // safe LOWER bound on dist(p_j,c)
    const bool skip = (lb > 0.0f) && (lb * lb * 0.98f >= bvf);
    if (!__all(skip)) {   // scalar branch: whole wave skips or none does
      kb = 0;
#pragma unroll
      for (int j = 0; j < 16; ++j) {
        const float d2 = exact_d2(px[j], py[j], pz[j], cx, cy, cz);
        const float nd = fminf(dd[j], d2);
        dd[j] = nd;
        const u64 k =
            ((u64)__float_as_uint(nd) << 32) | (u64)(~(unsigned)oi[j]);
        if (k > kb) kb = k;
      }
    }
  }
}

// ---------------- gather p1 (also output ip1) -------------------------------
__global__ void gather_p1_kernel(const float* __restrict__ pts,
                                 const int* __restrict__ fidx,
                                 float* __restrict__ p1,
                                 float* __restrict__ out_ip1) {
  const int i = blockIdx.x * 256 + threadIdx.x;
  if (i >= NA * 3) return;
  const int a = i / 3, c = i - a * 3;
  const int b = a >> 10;
  const int src = fidx[a];
  const float v = pts[((size_t)b * NPTS + src) * 3 + c];
  p1[i] = v;
  out_ip1[i] = v;
}

// ---------------- KNN v2: DPP everywhere (r13 WIN) --------------------------
__global__ __launch_bounds__(256) void knn_kernel(
    const float* __restrict__ pts, const float* __restrict__ p1,
    int* __restrict__ knn_i, float* __restrict__ knn_d,
    float* __restrict__ out_ip0) {
  const int wq = threadIdx.x >> 6;
  const int lane = threadIdx.x & 63;
  const int a = blockIdx.x * 4 + wq;
  const int b = a >> 10;
  const float* __restrict__ P = pts + (size_t)b * NPTS * 3;
  const float qx = p1[a * 3 + 0], qy = p1[a * 3 + 1], qz = p1[a * 3 + 2];
  const float INF = __builtin_inff();
  float D[16]; int I[16];
#pragma unroll
  for (int s = 0; s < 16; ++s) { D[s] = INF; I[s] = 0x7fffffff; }
  float wstar = INF;

  for (int s = 0; s < NPTS / 64; ++s) {
    const int idx = s * 64 + lane;
    const float x = P[idx * 3 + 0];
    const float y = P[idx * 3 + 1];
    const float z = P[idx * 3 + 2];
    const float d2 = exact_d2(x, y, z, qx, qy, qz);
    const bool pass = (d2 <= wstar);
    if (__any(pass)) {
      if (pass && dl_lt(d2, idx, D[15], I[15])) {
        bool c[16];
#pragma unroll
        for (int u = 0; u < 16; ++u) c[u] = dl_lt(d2, idx, D[u], I[u]);
#pragma unroll
        for (int u = 15; u >= 1; --u) {
          D[u] = c[u] ? (c[u - 1] ? D[u - 1] : d2) : D[u];
          I[u] = c[u] ? (c[u - 1] ? I[u - 1] : idx) : I[u];
        }
        if (c[0]) { D[0] = d2; I[0] = idx; }
      }
      float w = D[15];
      w = dpp_fmin_self<0x111>(w);
      w = dpp_fmin_self<0x112>(w);
      w = dpp_fmin_self<0x114>(w);
      w = dpp_fmin_self<0x118>(w);
      w = dpp_fmin_self<0x142>(w);
      w = dpp_fmin_self<0x143>(w);
      wstar = __int_as_float(
          __builtin_amdgcn_readlane(__float_as_int(w), 63));
    }
  }

  __shared__ u64 sk[4][1024];
#pragma unroll
  for (int u = 0; u < 16; ++u)
    sk[wq][lane * 16 + u] =
        ((u64)__float_as_uint(D[u]) << 32) | (unsigned)I[u];
  int head = lane * 16;
  const int hend = head + 16;
  u64 md = sk[wq][head];
  u64 outK = 0;
  for (int r = 0; r < 16; ++r) {
    u64 v = md;
    v = dpp_min_u64<0x111>(v);
    v = dpp_min_u64<0x112>(v);
    v = dpp_min_u64<0x114>(v);
    v = dpp_min_u64<0x118>(v);
    v = dpp_min_u64<0x142>(v);
    v = dpp_min_u64<0x143>(v);
    const unsigned glo =
        (unsigned)__builtin_amdgcn_readlane((int)(unsigned)v, 63);
    const unsigned ghi =
        (unsigned)__builtin_amdgcn_readlane((int)(unsigned)(v >> 32), 63);
    const u64 g = ((u64)ghi << 32) | glo;
    if (lane == r) outK = g;
    if (md == g) {
      ++head;
      md = (head < hend) ? sk[wq][head] : ~0ull;
    }
  }
  if (lane < 16) {
    const int o = a * 16 + lane;
    const int outI = (int)(unsigned)outK;
    knn_i[o] = outI;
    knn_d[o] = __uint_as_float((unsigned)(outK >> 32));
    out_ip0[(size_t)o * 3 + 0] = P[outI * 3 + 0];
    out_ip0[(size_t)o * 3 + 1] = P[outI * 3 + 1];
    out_ip0[(size_t)o * 3 + 2] = P[outI * 3 + 2];
  }
}

// ---------------- encoder 0: per-anchor shared MLP + max pool ---------------
__global__ __launch_bounds__(128) void enc0_kernel(
    const float* __restrict__ ip0, const float* __restrict__ knn_d,
    const float* __restrict__ p1, const float* __restrict__ W0a,
    const float* __restrict__ b0a, const float* __restrict__ W0b,
    const float* __restrict__ b0b, float* __restrict__ f0) {
  const int a = blockIdx.x;
  __shared__ float rel[16][4];
  __shared__ __align__(16) float h1s[16][64];
  const int t = threadIdx.x;
  if (t < 16) {
    const float ax = p1[a * 3 + 0], ay = p1[a * 3 + 1], az = p1[a * 3 + 2];
    const float kd = knn_d[a * 16 + t];
    const bool within = (kd <= 0.04f);
    const float* nb = ip0 + (size_t)(a * 16 + t) * 3;
    rel[t][0] = within ? (nb[0] - ax) * 5.0f : 0.0f;
    rel[t][1] = within ? (nb[1] - ay) * 5.0f : 0.0f;
    rel[t][2] = within ? (nb[2] - az) * 5.0f : 0.0f;
  }
  __syncthreads();
  {
    const int m = t & 63, kh = t >> 6;
    const float w0 = W0a[m], w1 = W0a[64 + m], w2 = W0a[128 + m];
    const float bb = b0a[m];
#pragma unroll
    for (int kk = 0; kk < 8; ++kk) {
      const int k = kh * 8 + kk;
      const float h =
          fmaf(rel[k][0], w0, fmaf(rel[k][1], w1, fmaf(rel[k][2], w2, bb)));
      h1s[k][m] = fmaxf(h, 0.0f);
    }
  }
  __syncthreads();
  {
    const int col = t;  // 0..127
    float acc[16];
#pragma unroll
    for (int k = 0; k < 16; ++k) acc[k] = 0.0f;
    for (int m = 0; m < 64; m += 4) {
      const float w0 = W0b[(m + 0) * 128 + col];
      const float w1 = W0b[(m + 1) * 128 + col];
      const float w2 = W0b[(m + 2) * 128 + col];
      const float w3 = W0b[(m + 3) * 128 + col];
#pragma unroll
      for (int k = 0; k < 16; ++k) {
        const float4 h = *(const float4*)&h1s[k][m];
        acc[k] = fmaf(h.x, w0, fmaf(h.y, w1, fmaf(h.z, w2, fmaf(h.w, w3, acc[k]))));
      }
    }
    float mx = acc[0];
#pragma unroll
    for (int k = 1; k < 16; ++k) mx = fmaxf(mx, acc[k]);
    f0[(size_t)a * 128 + col] = mx + b0b[col];
  }
}

// ---------------- build X1 = [p1*2 | f0 | 0pad] ------------------------------
__global__ void build_x1_kernel(const float* __restrict__ p1,
                                const float* __restrict__ f0,
                                float* __restrict__ X1) {
  const int i = blockIdx.x * 256 + threadIdx.x;
  if (i >= NA * 132) return;
  const int r = i / 132, c = i - r * 132;
  float v;
  if (c < 3) v = p1[r * 3 + c] * 2.0f;
  else if (c < 131) v = f0[(size_t)r * 128 + (c - 3)];
  else v = 0.0f;
  X1[i] = v;
}

// ---------------- generic 64x64 fp32 GEMM (+bias, optional relu/colmax) -----
template <int DO_RELU, int COLMAX>
__global__ __launch_bounds__(256) void gemm64_kernel(
    const float* __restrict__ A, const float* __restrict__ W,
    const float* __restrict__ bias, float* __restrict__ C, const int N,
    const int K, const int Kreal, const int lda, const int ldb) {
  __shared__ float As[64][33];
  __shared__ __align__(16) float Bs[32][64];
  __shared__ float red[16][64];
  const int t = threadIdx.x;
  const int tx = t & 15, ty = t >> 4;
  const int row0 = blockIdx.y * 64, col0 = blockIdx.x * 64;
  float acc[4][4] = {};
  for (int k0 = 0; k0 < K; k0 += 32) {
    {
      const int m = t >> 2, kk = (t & 3) * 8;
      const float* src = A + (size_t)(row0 + m) * lda + (k0 + kk);
#pragma unroll
      for (int u = 0; u < 8; ++u)
        As[m][kk + u] = (k0 + kk + u < Kreal) ? src[u] : 0.0f;
    }
    {
      const int kk = t >> 3, c = (t & 7) * 8;
      const int kg = k0 + kk;
      const float* src = W + (size_t)kg * ldb + (col0 + c);
      const bool ok = (kg < Kreal);
#pragma unroll
      for (int u = 0; u < 8; ++u) Bs[kk][c + u] = ok ? src[u] : 0.0f;
    }
    __syncthreads();
#pragma unroll
    for (int k = 0; k < 32; ++k) {
      const float a0 = As[ty * 4 + 0][k];
      const float a1 = As[ty * 4 + 1][k];
      const float a2 = As[ty * 4 + 2][k];
      const float a3 = As[ty * 4 + 3][k];
      const float4 bv = *(const float4*)&Bs[k][tx * 4];
      acc[0][0] = fmaf(a0, bv.x, acc[0][0]);
      acc[0][1] = fmaf(a0, bv.y, acc[0][1]);
      acc[0][2] = fmaf(a0, bv.z, acc[0][2]);
      acc[0][3] = fmaf(a0, bv.w, acc[0][3]);
      acc[1][0] = fmaf(a1, bv.x, acc[1][0]);
      acc[1][1] = fmaf(a1, bv.y, acc[1][1]);
      acc[1][2] = fmaf(a1, bv.z, acc[1][2]);
      acc[1][3] = fmaf(a1, bv.w, acc[1][3]);
      acc[2][0] = fmaf(a2, bv.x, acc[2][0]);
      acc[2][1] = fmaf(a2, bv.y, acc[2][1]);
      acc[2][2] = fmaf(a2, bv.z, acc[2][2]);
      acc[2][3] = fmaf(a2, bv.w, acc[2][3]);
      acc[3][0] = fmaf(a3, bv.x, acc[3][0]);
      acc[3][1] = fmaf(a3, bv.y, acc[3][1]);
      acc[3][2] = fmaf(a3, bv.z, acc[3][2]);
      acc[3][3] = fmaf(a3, bv.w, acc[3][3]);
    }
    __syncthreads();
  }
  const float b0v = bias[col0 + tx * 4 + 0];
  const float b1v = bias[col0 + tx * 4 + 1];
  const float b2v = bias[col0 + tx * 4 + 2];
  const float b3v = bias[col0 + tx * 4 + 3];
  if (COLMAX == 0) {
#pragma unroll
    for (int i = 0; i < 4; ++i) {
      float4 v;
      v.x = acc[i][0] + b0v;
      v.y = acc[i][1] + b1v;
      v.z = acc[i][2] + b2v;
      v.w = acc[i][3] + b3v;
      if (DO_RELU) {
        v.x = fmaxf(v.x, 0.0f); v.y = fmaxf(v.y, 0.0f);
        v.z = fmaxf(v.z, 0.0f); v.w = fmaxf(v.w, 0.0f);
      }
      *(float4*)&C[(size_t)(row0 + ty * 4 + i) * N + col0 + tx * 4] = v;
    }
  } else {
    const float m0 =
        fmaxf(fmaxf(acc[0][0], acc[1][0]), fmaxf(acc[2][0], acc[3][0])) + b0v;
    const float m1 =
        fmaxf(fmaxf(acc[0][1], acc[1][1]), fmaxf(acc[2][1], acc[3][1])) + b1v;
    const float m2 =
        fmaxf(fmaxf(acc[0][2], acc[1][2]), fmaxf(acc[2][2], acc[3][2])) + b2v;
    const float m3 =
        fmaxf(fmaxf(acc[0][3], acc[1][3]), fmaxf(acc[2][3], acc[3][3])) + b3v;
    red[ty][tx * 4 + 0] = m0;
    red[ty][tx * 4 + 1] = m1;
    red[ty][tx * 4 + 2] = m2;
    red[ty][tx * 4 + 3] = m3;
    __syncthreads();
    if (t < 64) {
      float mm = red[0][t];
#pragma unroll
      for (int r = 1; r < 16; ++r) mm = fmaxf(mm, red[r][t]);
      C[(size_t)(row0 >> 6) * N + col0 + t] = mm;
    }
  }
}

// ---------------- fused z-max + zW = z @ Wd0a[:512,:] (r13 WIN) -------------
__global__ __launch_bounds__(1024) void zwfused_kernel(
    const float* __restrict__ pmax, const float* __restrict__ Wd0a,
    float* __restrict__ outz, float* __restrict__ zW) {
  const int b = blockIdx.x;
  const int t = threadIdx.x;
  __shared__ float zs[512];
  __shared__ float part[4][256];
  if (t < 512) {
    float m = pmax[(size_t)(b * 16) * 512 + t];
#pragma unroll
    for (int rt = 1; rt < 16; ++rt)
      m = fmaxf(m, pmax[(size_t)(b * 16 + rt) * 512 + t]);
    zs[t] = m;
    outz[b * 512 + t] = m;
  }
  __syncthreads();
  const int c = t & 255;
  const int ch = t >> 8;
  const int q0 = ch * 128;
  float acc = 0.0f;
  for (int q = 0; q < 128; q += 4) {
    acc = fmaf(zs[q0 + q + 0], Wd0a[(q0 + q + 0) * 256 + c], acc);
    acc = fmaf(zs[q0 + q + 1], Wd0a[(q0 + q + 1) * 256 + c], acc);
    acc = fmaf(zs[q0 + q + 2], Wd0a[(q0 + q + 2) * 256 + c], acc);
    acc = fmaf(zs[q0 + q + 3], Wd0a[(q0 + q + 3) * 256 + c], acc);
  }
  part[ch][c] = acc;
  __syncthreads();
  if (t < 256)
    zW[b * 256 + t] =
        (part[0][t] + part[1][t]) + (part[2][t] + part[3][t]);
}

// ---------------- decoder 0: hd0 -> fdec, relp0(out1) -----------------------
__global__ __launch_bounds__(256) void dec0_kernel(
    const float* __restrict__ zW, const float* __restrict__ grid0,
    const float* __restrict__ Wd0a, const float* __restrict__ bd0a,
    const float* __restrict__ Wf0, const float* __restrict__ Wp0,
    float* __restrict__ fdec, float* __restrict__ out_out1) {
  const int blk = blockIdx.x;
  const int b = blk >> 5;
  const int m0 = (blk & 31) * 32;
  __shared__ __align__(16) float hd0s[32][256];
  __shared__ float g0s[32][2];
  __shared__ float wp0s[768];
  const int t = threadIdx.x;
  if (t < 64) {
    const int r = t >> 1, cc = t & 1;
    g0s[r][cc] = grid0[(m0 + r) * 2 + cc];
  }
  wp0s[t] = Wp0[t];
  wp0s[256 + t] = Wp0[256 + t];
  wp0s[512 + t] = Wp0[512 + t];
  __syncthreads();
  {
    const int c = t;
    const float w0 = Wd0a[512 * 256 + c];
    const float w1 = Wd0a[513 * 256 + c];
    const float basev = zW[b * 256 + c] + bd0a[c];
#pragma unroll 8
    for (int r = 0; r < 32; ++r) {
      const float h = fmaf(g0s[r][0], w0, fmaf(g0s[r][1], w1, basev));
      hd0s[r][c] = fmaxf(h, 0.0f);
    }
  }
  __syncthreads();
  {
    const int c = t & 127;
    const int rh = (t >> 7) * 16;
    float acc[16];
#pragma unroll
    for (int r = 0; r < 16; ++r) acc[r] = 0.0f;
    for (int q = 0; q < 256; q += 4) {
      const float w0 = Wf0[(q + 0) * 128 + c];
      const float w1 = Wf0[(q + 1) * 128 + c];
      const float w2 = Wf0[(q + 2) * 128 + c];
      const float w3 = Wf0[(q + 3) * 128 + c];
#pragma unroll
      for (int r = 0; r < 16; ++r) {
        const float4 h = *(const float4*)&hd0s[rh + r][q];
        acc[r] = fmaf(h.x, w0, fmaf(h.y, w1, fmaf(h.z, w2, fmaf(h.w, w3, acc[r]))));
      }
    }
    const size_t g0i = ((size_t)(b * M1 + m0 + rh)) * 128 + c;
#pragma unroll
    for (int r = 0; r < 16; ++r) fdec[g0i + (size_t)r * 128] = acc[r];
  }
  if (t < 96) {
    const int m = t / 3;
    const int c = t - m * 3;
    float acc = 0.0f;
    for (int q = 0; q < 256; ++q) acc = fmaf(hd0s[m][q], wp0s[q * 3 + c], acc);
    out_out1[((size_t)(b * M1 + m0 + m)) * 3 + c] = acc * 0.5f;
  }
}

// ---------------- decoder 1: per-anchor folding MLP -> out0 -----------------
__global__ __launch_bounds__(256) void dec1_kernel(
    const float* __restrict__ fdec, const float* __restrict__ grid1,
    const float* __restrict__ Wd1a, const float* __restrict__ bd1a,
    const float* __restrict__ Wp1, const float* __restrict__ out1r,
    float* __restrict__ out0w) {
  const int a0 = blockIdx.x * 16;
  __shared__ __align__(16) float fds[16][128];
  __shared__ __align__(16) float gs[16][128];
  __shared__ __align__(16) float us[16][128];
  __shared__ __align__(16) float wp1t[3][128];
  __shared__ float o1s[16][3];
  const int t = threadIdx.x;
  {
    const int r = t >> 4;
    const int c0 = (t & 15) * 8;
    const float* src = fdec + ((size_t)(a0 + r)) * 128 + c0;
#pragma unroll
    for (int u = 0; u < 8; ++u) fds[r][c0 + u] = src[u];
  }
  {
    const int k = t >> 4;
    const int c0 = (t & 15) * 8;
    const float g0 = grid1[k * 2 + 0];
    const float g1 = grid1[k * 2 + 1];
#pragma unroll
    for (int u = 0; u < 8; ++u) {
      const int c = c0 + u;
      gs[k][c] = fmaf(g0, Wd1a[128 * 128 + c], fmaf(g1, Wd1a[129 * 128 + c], bd1a[c]));
    }
  }
  if (t < 128) {
    wp1t[0][t] = Wp1[t * 3 + 0];
    wp1t[1][t] = Wp1[t * 3 + 1];
    wp1t[2][t] = Wp1[t * 3 + 2];
  }
  if (t < 48) {
    const int r = t / 3, c = t - r * 3;
    o1s[r][c] = out1r[((size_t)(a0 + r)) * 3 + c];
  }
  __syncthreads();
  {
    const int c = t & 127;
    const int mh = (t >> 7) * 8;
    float acc[8];
#pragma unroll
    for (int r = 0; r < 8; ++r) acc[r] = 0.0f;
    for (int q = 0; q < 128; q += 4) {
      const float w0 = Wd1a[(q + 0) * 128 + c];
      const float w1 = Wd1a[(q + 1) * 128 + c];
      const float w2 = Wd1a[(q + 2) * 128 + c];
      const float w3 = Wd1a[(q + 3) * 128 + c];
#pragma unroll
      for (int r = 0; r < 8; ++r) {
        const float4 f = *(const float4*)&fds[mh + r][q];
        acc[r] = fmaf(f.x, w0, fmaf(f.y, w1, fmaf(f.z, w2, fmaf(f.w, w3, acc[r]))));
      }
    }
#pragma unroll
    for (int r = 0; r < 8; ++r) us[mh + r][c] = acc[r];
  }
  __syncthreads();
  {
    const int m = t >> 4, k = t & 15;
    float a0v = 0.0f, a1v = 0.0f, a2v = 0.0f;
    for (int c = 0; c < 128; c += 4) {
      const float4 uu = *(const float4*)&us[m][c];
      const float4 gg = *(const float4*)&gs[k][c];
      const float h0 = fmaxf(uu.x + gg.x, 0.0f);
      const float h1 = fmaxf(uu.y + gg.y, 0.0f);
      const float h2 = fmaxf(uu.z + gg.z, 0.0f);
      const float h3 = fmaxf(uu.w + gg.w, 0.0f);
      const float4 wx = *(const float4*)&wp1t[0][c];
      const float4 wy = *(const float4*)&wp1t[1][c];
      const float4 wz = *(const float4*)&wp1t[2][c];
      a0v = fmaf(h0, wx.x, fmaf(h1, wx.y, fmaf(h2, wx.z, fmaf(h3, wx.w, a0v))));
      a1v = fmaf(h0, wy.x, fmaf(h1, wy.y, fmaf(h2, wy.z, fmaf(h3, wy.w, a1v))));
      a2v = fmaf(h0, wz.x, fmaf(h1, wz.y, fmaf(h2, wz.z, fmaf(h3, wz.w, a2v))));
    }
    const size_t o = (((size_t)(a0 + m)) * 16 + k) * 3;
    out0w[o + 0] = o1s[m][0] + a0v * 0.2f;
    out0w[o + 1] = o1s[m][1] + a1v * 0.2f;
    out0w[o + 2] = o1s[m][2] + a2v * 0.2f;
  }
}

extern "C" void kernel_launch(void* const* d_in, const int* in_sizes, int n_in,
                              void* d_out_v, int out_size, void* d_ws,
                              size_t ws_size, hipStream_t stream) {
  (void)in_sizes; (void)n_in; (void)out_size; (void)ws_size;
  const float* points = (const float*)d_in[0];
  const float* W0a = (const float*)d_in[1];
  const float* b0a = (const float*)d_in[2];
  const float* W0b = (const float*)d_in[3];
  const float* b0b = (const float*)d_in[4];
  const float* W1a = (const float*)d_in[5];
  const float* b1a = (const float*)d_in[6];
  const float* W1b = (const float*)d_in[7];
  const float* b1b = (const float*)d_in[8];
  const float* grid0 = (const float*)d_in[9];
  const float* Wd0a = (const float*)d_in[10];
  const float* bd0a = (const float*)d_in[11];
  const float* Wp0 = (const float*)d_in[12];
  const float* Wf0 = (const float*)d_in[13];
  const float* grid1 = (const float*)d_in[14];
  const float* Wd1a = (const float*)d_in[15];
  const float* bd1a = (const float*)d_in[16];
  const float* Wp1 = (const float*)d_in[17];
  float* out = (float*)d_out_v;
  char* ws = (char*)d_ws;

  int* fidx = (int*)(ws + 0);
  int* knn_i = (int*)(ws + 32768);
  float* knn_d = (float*)(ws + 557056);
  float* p1 = (float*)(ws + 1081344);
  float* f0 = (float*)(ws + 1179648);
  float* X1 = (float*)(ws + 5373952);
  float* mid1 = (float*)(ws + 9699328);
  int* perm = (int*)(ws + 12000000);
  float* pmax = (float*)(ws + 18087936);
  float* zW = (float*)(ws + 18366464);
  float* fdec = (float*)(ws + 18374656);

  sort_kernel<<<NB, 1024, 0, stream>>>(points, perm);
  fps_kernel<<<NB, 1024, 0, stream>>>(points, perm, fidx);
  gather_p1_kernel<<<(NA * 3 + 255) / 256, 256, 0, stream>>>(points, fidx, p1,
                                                             out + OUT_IP1);
  knn_kernel<<<NA / 4, 256, 0, stream>>>(points, p1, knn_i, knn_d,
                                         out + OUT_IP0);
  enc0_kernel<<<NA, 128, 0, stream>>>(out + OUT_IP0, knn_d, p1, W0a, b0a, W0b,
                                      b0b, f0);
  build_x1_kernel<<<(NA * 132 + 255) / 256, 256, 0, stream>>>(p1, f0, X1);
  gemm64_kernel<1, 0><<<dim3(4, 128), 256, 0, stream>>>(X1, W1a, b1a, mid1,
                                                        256, 132, 131, 132, 256);
  gemm64_kernel<0, 1><<<dim3(8, 128), 256, 0, stream>>>(mid1, W1b, b1b, pmax,
                                                        512, 256, 256, 256, 512);
  zwfused_kernel<<<NB, 1024, 0, stream>>>(pmax, Wd0a, out + OUT_Z, zW);
  dec0_kernel<<<256, 256, 0, stream>>>(zW, grid0, Wd0a, bd0a, Wf0, Wp0, fdec,
                                       out + OUT_OUT1);
  dec1_kernel<<<NA / 16, 256, 0, stream>>>(fdec, grid1, Wd1a, bd1a, Wp1,
                                           out + OUT_OUT1, out + OUT_OUT0);
}

// Round 19
// 2275.406 us; speedup vs baseline: 1.3373x; 1.1878x over previous
//
#include <hip/hip_runtime.h>

#define NB 8
#define NPTS 16384
#define M1 1024
#define NA 8192

// d_out float offsets
#define OUT_IP0  0
#define OUT_IP1  393216
#define OUT_OUT0 417792
#define OUT_OUT1 811008
#define OUT_Z    835584

typedef unsigned long long u64;

__device__ __forceinline__ float exact_d2(float ax, float ay, float az,
                                          float bx, float by, float bz) {
  float dx = __fsub_rn(ax, bx);
  float dy = __fsub_rn(ay, by);
  float dz = __fsub_rn(az, bz);
  return __fadd_rn(__fadd_rn(__fmul_rn(dx, dx), __fmul_rn(dy, dy)),
                   __fmul_rn(dz, dz));
}

__device__ __forceinline__ bool dl_lt(float d1, int i1, float d2, int i2) {
  return (d1 < d2) || ((d1 == d2) && (i1 < i2));
}

// DPP fmax step (v9b WIN): old=0, bound_ctrl=1 -> OOB lanes inject 0.0,
// harmless for max over d2 >= 0.
template <int CTRL>
__device__ __forceinline__ float dpp_fmax(float v) {
  const int s =
      __builtin_amdgcn_update_dpp(0, __float_as_int(v), CTRL, 0xf, 0xf, true);
  return fmaxf(v, __int_as_float(s));
}

// DPP fmin step: old=SELF, bound_ctrl=0 -> OOB lanes combine self (no-op).
template <int CTRL>
__device__ __forceinline__ float dpp_fmin_self(float v) {
  const int s = __builtin_amdgcn_update_dpp(__float_as_int(v),
                                            __float_as_int(v), CTRL, 0xf, 0xf,
                                            false);
  return fminf(v, __int_as_float(s));
}

// DPP u64-min step (old=self): 2x 32-bit DPP moves + one u64 compare-select.
template <int CTRL>
__device__ __forceinline__ u64 dpp_min_u64(u64 v) {
  const int lo = (int)(unsigned)v;
  const int hi = (int)(unsigned)(v >> 32);
  const int slo = __builtin_amdgcn_update_dpp(lo, lo, CTRL, 0xf, 0xf, false);
  const int shi = __builtin_amdgcn_update_dpp(hi, hi, CTRL, 0xf, 0xf, false);
  const u64 s = ((u64)(unsigned)shi << 32) | (unsigned)slo;
  return s < v ? s : v;
}

// ---------------- FPS v10 (best measured: 1485us; r13 config) ---------------
// Issue-bound at ~86% active-CU VALUBusy; backend pins VGPRs ~40-64 and
// spills/reloads per-thread arrays regardless of structure (v4-v13, six
// variants). Best variant: all state nominally in regs, 82KB LDS pad pins
// 1 block/CU, DPP wave max + LDS atomicMax block reduce, scalar winner loads.
// Bucketed-skip variants (r17/r18) lose: skip metadata deepens spills more
// than skips save. This is the locked configuration.
__global__ __launch_bounds__(1024) void fps_kernel(
    const float* __restrict__ pts, int* __restrict__ fidx) {
  const int b = blockIdx.x;
  const float* __restrict__ P = pts + (size_t)b * NPTS * 3;
  const int t = threadIdx.x;
  const int lane = t & 63;

  __shared__ u64 s_slot[3];
  __shared__ char s_pad[81920];  // occupancy governor: 1 block/CU
  if ((int)blockIdx.x == -1) ((volatile char*)s_pad)[0] = 1;  // keep alive

  float px[16], py[16], pz[16], dd[16];
  const float sx = P[0], sy = P[1], sz = P[2];
  const int base = t * 16;
  float bv = -1.0f;  // all d2 >= 0; strict > keeps lowest j
  int bj = 0;
#pragma unroll
  for (int j = 0; j < 16; ++j) {
    const float x = P[(base + j) * 3 + 0];
    const float y = P[(base + j) * 3 + 1];
    const float z = P[(base + j) * 3 + 2];
    px[j] = x; py[j] = y; pz[j] = z;
    const float d = exact_d2(x, y, z, sx, sy, sz);
    dd[j] = d;
    if (d > bv) { bv = d; bj = j; }
  }
  if (t == 0) {
    fidx[b * M1 + 0] = 0;
    s_slot[0] = 0; s_slot[1] = 0; s_slot[2] = 0;
  }
  __syncthreads();  // order slot init before iteration-1 atomics

  for (int it = 1; it < M1; ++it) {
    const int par = it % 3;
    const int nxt = (it + 1) % 3;
    // ---- wave max via DPP (all VALU) ----
    float wm = bv;
    wm = dpp_fmax<0x111>(wm);  // row_shr:1
    wm = dpp_fmax<0x112>(wm);  // row_shr:2
    wm = dpp_fmax<0x114>(wm);  // row_shr:4
    wm = dpp_fmax<0x118>(wm);  // row_shr:8
    wm = dpp_fmax<0x142>(wm);  // row_bcast:15
    wm = dpp_fmax<0x143>(wm);  // row_bcast:31
    wm = __int_as_float(
        __builtin_amdgcn_readlane(__float_as_int(wm), 63));  // uniform
    // lowest lane holding wm == lowest point index within wave
    const unsigned long long msk = __ballot(bv == wm);
    const int l0 = (int)__ffsll((long long)msk) - 1;
    const int wbi = __builtin_amdgcn_readlane(base + bj, l0);
    if (lane == 0) {
      const u64 key =
          ((u64)__float_as_uint(wm) << 32) | (u64)(~(unsigned)wbi);
      atomicMax(&s_slot[par], key);
    }
    if (t == 0) s_slot[nxt] = 0;  // readers finished before previous barrier
    __syncthreads();
    const u64 g = s_slot[par];  // broadcast read, conflict-free
    const int wi = __builtin_amdgcn_readfirstlane((int)(~(unsigned)g));
    if (t == 0) fidx[b * M1 + it] = wi;
    const float cx = P[wi * 3 + 0];  // uniform -> scalar loads -> SGPRs
    const float cy = P[wi * 3 + 1];
    const float cz = P[wi * 3 + 2];
    bv = -1.0f; bj = 0;
#pragma unroll
    for (int j = 0; j < 16; ++j) {
      const float d2 = exact_d2(px[j], py[j], pz[j], cx, cy, cz);
      const float nd = fminf(dd[j], d2);
      dd[j] = nd;
      if (nd > bv) { bv = nd; bj = j; }
    }
  }
}

// ---------------- gather p1 (also output ip1) -------------------------------
__global__ void gather_p1_kernel(const float* __restrict__ pts,
                                 const int* __restrict__ fidx,
                                 float* __restrict__ p1,
                                 float* __restrict__ out_ip1) {
  const int i = blockIdx.x * 256 + threadIdx.x;
  if (i >= NA * 3) return;
  const int a = i / 3, c = i - a * 3;
  const int b = a >> 10;
  const int src = fidx[a];
  const float v = pts[((size_t)b * NPTS + src) * 3 + c];
  p1[i] = v;
  out_ip1[i] = v;
}

// ---------------- KNN v2: DPP everywhere (r13 WIN) --------------------------
__global__ __launch_bounds__(256) void knn_kernel(
    const float* __restrict__ pts, const float* __restrict__ p1,
    int* __restrict__ knn_i, float* __restrict__ knn_d,
    float* __restrict__ out_ip0) {
  const int wq = threadIdx.x >> 6;
  const int lane = threadIdx.x & 63;
  const int a = blockIdx.x * 4 + wq;
  const int b = a >> 10;
  const float* __restrict__ P = pts + (size_t)b * NPTS * 3;
  const float qx = p1[a * 3 + 0], qy = p1[a * 3 + 1], qz = p1[a * 3 + 2];
  const float INF = __builtin_inff();
  float D[16]; int I[16];
#pragma unroll
  for (int s = 0; s < 16; ++s) { D[s] = INF; I[s] = 0x7fffffff; }
  float wstar = INF;

  for (int s = 0; s < NPTS / 64; ++s) {
    const int idx = s * 64 + lane;
    const float x = P[idx * 3 + 0];
    const float y = P[idx * 3 + 1];
    const float z = P[idx * 3 + 2];
    const float d2 = exact_d2(x, y, z, qx, qy, qz);
    const bool pass = (d2 <= wstar);
    if (__any(pass)) {
      if (pass && dl_lt(d2, idx, D[15], I[15])) {
        bool c[16];
#pragma unroll
        for (int u = 0; u < 16; ++u) c[u] = dl_lt(d2, idx, D[u], I[u]);
#pragma unroll
        for (int u = 15; u >= 1; --u) {
          D[u] = c[u] ? (c[u - 1] ? D[u - 1] : d2) : D[u];
          I[u] = c[u] ? (c[u - 1] ? I[u - 1] : idx) : I[u];
        }
        if (c[0]) { D[0] = d2; I[0] = idx; }
      }
      float w = D[15];
      w = dpp_fmin_self<0x111>(w);
      w = dpp_fmin_self<0x112>(w);
      w = dpp_fmin_self<0x114>(w);
      w = dpp_fmin_self<0x118>(w);
      w = dpp_fmin_self<0x142>(w);
      w = dpp_fmin_self<0x143>(w);
      wstar = __int_as_float(
          __builtin_amdgcn_readlane(__float_as_int(w), 63));
    }
  }

  // merge: extract 16 global minima by (d2, idx) — u64 keys, DPP min
  __shared__ u64 sk[4][1024];
#pragma unroll
  for (int u = 0; u < 16; ++u)
    sk[wq][lane * 16 + u] =
        ((u64)__float_as_uint(D[u]) << 32) | (unsigned)I[u];
  int head = lane * 16;
  const int hend = head + 16;
  u64 md = sk[wq][head];
  u64 outK = 0;
  for (int r = 0; r < 16; ++r) {
    u64 v = md;
    v = dpp_min_u64<0x111>(v);
    v = dpp_min_u64<0x112>(v);
    v = dpp_min_u64<0x114>(v);
    v = dpp_min_u64<0x118>(v);
    v = dpp_min_u64<0x142>(v);
    v = dpp_min_u64<0x143>(v);
    const unsigned glo =
        (unsigned)__builtin_amdgcn_readlane((int)(unsigned)v, 63);
    const unsigned ghi =
        (unsigned)__builtin_amdgcn_readlane((int)(unsigned)(v >> 32), 63);
    const u64 g = ((u64)ghi << 32) | glo;
    if (lane == r) outK = g;
    if (md == g) {  // unique keys -> exactly one owner advances
      ++head;
      md = (head < hend) ? sk[wq][head] : ~0ull;
    }
  }
  if (lane < 16) {
    const int o = a * 16 + lane;
    const int outI = (int)(unsigned)outK;
    knn_i[o] = outI;
    knn_d[o] = __uint_as_float((unsigned)(outK >> 32));
    out_ip0[(size_t)o * 3 + 0] = P[outI * 3 + 0];
    out_ip0[(size_t)o * 3 + 1] = P[outI * 3 + 1];
    out_ip0[(size_t)o * 3 + 2] = P[outI * 3 + 2];
  }
}

// ---------------- encoder 0: per-anchor shared MLP + max pool ---------------
__global__ __launch_bounds__(128) void enc0_kernel(
    const float* __restrict__ ip0, const float* __restrict__ knn_d,
    const float* __restrict__ p1, const float* __restrict__ W0a,
    const float* __restrict__ b0a, const float* __restrict__ W0b,
    const float* __restrict__ b0b, float* __restrict__ f0) {
  const int a = blockIdx.x;
  __shared__ float rel[16][4];
  __shared__ __align__(16) float h1s[16][64];
  const int t = threadIdx.x;
  if (t < 16) {
    const float ax = p1[a * 3 + 0], ay = p1[a * 3 + 1], az = p1[a * 3 + 2];
    const float kd = knn_d[a * 16 + t];
    const bool within = (kd <= 0.04f);
    const float* nb = ip0 + (size_t)(a * 16 + t) * 3;
    rel[t][0] = within ? (nb[0] - ax) * 5.0f : 0.0f;
    rel[t][1] = within ? (nb[1] - ay) * 5.0f : 0.0f;
    rel[t][2] = within ? (nb[2] - az) * 5.0f : 0.0f;
  }
  __syncthreads();
  {
    const int m = t & 63, kh = t >> 6;
    const float w0 = W0a[m], w1 = W0a[64 + m], w2 = W0a[128 + m];
    const float bb = b0a[m];
#pragma unroll
    for (int kk = 0; kk < 8; ++kk) {
      const int k = kh * 8 + kk;
      const float h =
          fmaf(rel[k][0], w0, fmaf(rel[k][1], w1, fmaf(rel[k][2], w2, bb)));
      h1s[k][m] = fmaxf(h, 0.0f);
    }
  }
  __syncthreads();
  {
    const int col = t;  // 0..127
    float acc[16];
#pragma unroll
    for (int k = 0; k < 16; ++k) acc[k] = 0.0f;
    for (int m = 0; m < 64; m += 4) {
      const float w0 = W0b[(m + 0) * 128 + col];
      const float w1 = W0b[(m + 1) * 128 + col];
      const float w2 = W0b[(m + 2) * 128 + col];
      const float w3 = W0b[(m + 3) * 128 + col];
#pragma unroll
      for (int k = 0; k < 16; ++k) {
        const float4 h = *(const float4*)&h1s[k][m];
        acc[k] = fmaf(h.x, w0, fmaf(h.y, w1, fmaf(h.z, w2, fmaf(h.w, w3, acc[k]))));
      }
    }
    float mx = acc[0];
#pragma unroll
    for (int k = 1; k < 16; ++k) mx = fmaxf(mx, acc[k]);
    f0[(size_t)a * 128 + col] = mx + b0b[col];
  }
}

// ---------------- build X1 = [p1*2 | f0 | 0pad] ------------------------------
__global__ void build_x1_kernel(const float* __restrict__ p1,
                                const float* __restrict__ f0,
                                float* __restrict__ X1) {
  const int i = blockIdx.x * 256 + threadIdx.x;
  if (i >= NA * 132) return;
  const int r = i / 132, c = i - r * 132;
  float v;
  if (c < 3) v = p1[r * 3 + c] * 2.0f;
  else if (c < 131) v = f0[(size_t)r * 128 + (c - 3)];
  else v = 0.0f;
  X1[i] = v;
}

// ---------------- generic 64x64 fp32 GEMM (+bias, optional relu/colmax) -----
template <int DO_RELU, int COLMAX>
__global__ __launch_bounds__(256) void gemm64_kernel(
    const float* __restrict__ A, const float* __restrict__ W,
    const float* __restrict__ bias, float* __restrict__ C, const int N,
    const int K, const int Kreal, const int lda, const int ldb) {
  __shared__ float As[64][33];
  __shared__ __align__(16) float Bs[32][64];
  __shared__ float red[16][64];
  const int t = threadIdx.x;
  const int tx = t & 15, ty = t >> 4;
  const int row0 = blockIdx.y * 64, col0 = blockIdx.x * 64;
  float acc[4][4] = {};
  for (int k0 = 0; k0 < K; k0 += 32) {
    {
      const int m = t >> 2, kk = (t & 3) * 8;
      const float* src = A + (size_t)(row0 + m) * lda + (k0 + kk);
#pragma unroll
      for (int u = 0; u < 8; ++u)
        As[m][kk + u] = (k0 + kk + u < Kreal) ? src[u] : 0.0f;
    }
    {
      const int kk = t >> 3, c = (t & 7) * 8;
      const int kg = k0 + kk;
      const float* src = W + (size_t)kg * ldb + (col0 + c);
      const bool ok = (kg < Kreal);
#pragma unroll
      for (int u = 0; u < 8; ++u) Bs[kk][c + u] = ok ? src[u] : 0.0f;
    }
    __syncthreads();
#pragma unroll
    for (int k = 0; k < 32; ++k) {
      const float a0 = As[ty * 4 + 0][k];
      const float a1 = As[ty * 4 + 1][k];
      const float a2 = As[ty * 4 + 2][k];
      const float a3 = As[ty * 4 + 3][k];
      const float4 bv = *(const float4*)&Bs[k][tx * 4];
      acc[0][0] = fmaf(a0, bv.x, acc[0][0]);
      acc[0][1] = fmaf(a0, bv.y, acc[0][1]);
      acc[0][2] = fmaf(a0, bv.z, acc[0][2]);
      acc[0][3] = fmaf(a0, bv.w, acc[0][3]);
      acc[1][0] = fmaf(a1, bv.x, acc[1][0]);
      acc[1][1] = fmaf(a1, bv.y, acc[1][1]);
      acc[1][2] = fmaf(a1, bv.z, acc[1][2]);
      acc[1][3] = fmaf(a1, bv.w, acc[1][3]);
      acc[2][0] = fmaf(a2, bv.x, acc[2][0]);
      acc[2][1] = fmaf(a2, bv.y, acc[2][1]);
      acc[2][2] = fmaf(a2, bv.z, acc[2][2]);
      acc[2][3] = fmaf(a2, bv.w, acc[2][3]);
      acc[3][0] = fmaf(a3, bv.x, acc[3][0]);
      acc[3][1] = fmaf(a3, bv.y, acc[3][1]);
      acc[3][2] = fmaf(a3, bv.z, acc[3][2]);
      acc[3][3] = fmaf(a3, bv.w, acc[3][3]);
    }
    __syncthreads();
  }
  const float b0v = bias[col0 + tx * 4 + 0];
  const float b1v = bias[col0 + tx * 4 + 1];
  const float b2v = bias[col0 + tx * 4 + 2];
  const float b3v = bias[col0 + tx * 4 + 3];
  if (COLMAX == 0) {
#pragma unroll
    for (int i = 0; i < 4; ++i) {
      float4 v;
      v.x = acc[i][0] + b0v;
      v.y = acc[i][1] + b1v;
      v.z = acc[i][2] + b2v;
      v.w = acc[i][3] + b3v;
      if (DO_RELU) {
        v.x = fmaxf(v.x, 0.0f); v.y = fmaxf(v.y, 0.0f);
        v.z = fmaxf(v.z, 0.0f); v.w = fmaxf(v.w, 0.0f);
      }
      *(float4*)&C[(size_t)(row0 + ty * 4 + i) * N + col0 + tx * 4] = v;
    }
  } else {
    const float m0 =
        fmaxf(fmaxf(acc[0][0], acc[1][0]), fmaxf(acc[2][0], acc[3][0])) + b0v;
    const float m1 =
        fmaxf(fmaxf(acc[0][1], acc[1][1]), fmaxf(acc[2][1], acc[3][1])) + b1v;
    const float m2 =
        fmaxf(fmaxf(acc[0][2], acc[1][2]), fmaxf(acc[2][2], acc[3][2])) + b2v;
    const float m3 =
        fmaxf(fmaxf(acc[0][3], acc[1][3]), fmaxf(acc[2][3], acc[3][3])) + b3v;
    red[ty][tx * 4 + 0] = m0;
    red[ty][tx * 4 + 1] = m1;
    red[ty][tx * 4 + 2] = m2;
    red[ty][tx * 4 + 3] = m3;
    __syncthreads();
    if (t < 64) {
      float mm = red[0][t];
#pragma unroll
      for (int r = 1; r < 16; ++r) mm = fmaxf(mm, red[r][t]);
      C[(size_t)(row0 >> 6) * N + col0 + t] = mm;
    }
  }
}

// ---------------- fused z-max + zW = z @ Wd0a[:512,:] (r13 WIN) -------------
__global__ __launch_bounds__(1024) void zwfused_kernel(
    const float* __restrict__ pmax, const float* __restrict__ Wd0a,
    float* __restrict__ outz, float* __restrict__ zW) {
  const int b = blockIdx.x;
  const int t = threadIdx.x;
  __shared__ float zs[512];
  __shared__ float part[4][256];
  if (t < 512) {
    float m = pmax[(size_t)(b * 16) * 512 + t];
#pragma unroll
    for (int rt = 1; rt < 16; ++rt)
      m = fmaxf(m, pmax[(size_t)(b * 16 + rt) * 512 + t]);
    zs[t] = m;
    outz[b * 512 + t] = m;
  }
  __syncthreads();
  const int c = t & 255;
  const int ch = t >> 8;
  const int q0 = ch * 128;
  float acc = 0.0f;
  for (int q = 0; q < 128; q += 4) {
    acc = fmaf(zs[q0 + q + 0], Wd0a[(q0 + q + 0) * 256 + c], acc);
    acc = fmaf(zs[q0 + q + 1], Wd0a[(q0 + q + 1) * 256 + c], acc);
    acc = fmaf(zs[q0 + q + 2], Wd0a[(q0 + q + 2) * 256 + c], acc);
    acc = fmaf(zs[q0 + q + 3], Wd0a[(q0 + q + 3) * 256 + c], acc);
  }
  part[ch][c] = acc;
  __syncthreads();
  if (t < 256)
    zW[b * 256 + t] =
        (part[0][t] + part[1][t]) + (part[2][t] + part[3][t]);
}

// ---------------- decoder 0: hd0 -> fdec, relp0(out1) -----------------------
__global__ __launch_bounds__(256) void dec0_kernel(
    const float* __restrict__ zW, const float* __restrict__ grid0,
    const float* __restrict__ Wd0a, const float* __restrict__ bd0a,
    const float* __restrict__ Wf0, const float* __restrict__ Wp0,
    float* __restrict__ fdec, float* __restrict__ out_out1) {
  const int blk = blockIdx.x;
  const int b = blk >> 5;
  const int m0 = (blk & 31) * 32;
  __shared__ __align__(16) float hd0s[32][256];
  __shared__ float g0s[32][2];
  __shared__ float wp0s[768];
  const int t = threadIdx.x;
  if (t < 64) {
    const int r = t >> 1, cc = t & 1;
    g0s[r][cc] = grid0[(m0 + r) * 2 + cc];
  }
  wp0s[t] = Wp0[t];
  wp0s[256 + t] = Wp0[256 + t];
  wp0s[512 + t] = Wp0[512 + t];
  __syncthreads();
  {
    const int c = t;
    const float w0 = Wd0a[512 * 256 + c];
    const float w1 = Wd0a[513 * 256 + c];
    const float basev = zW[b * 256 + c] + bd0a[c];
#pragma unroll 8
    for (int r = 0; r < 32; ++r) {
      const float h = fmaf(g0s[r][0], w0, fmaf(g0s[r][1], w1, basev));
      hd0s[r][c] = fmaxf(h, 0.0f);
    }
  }
  __syncthreads();
  {
    const int c = t & 127;
    const int rh = (t >> 7) * 16;
    float acc[16];
#pragma unroll
    for (int r = 0; r < 16; ++r) acc[r] = 0.0f;
    for (int q = 0; q < 256; q += 4) {
      const float w0 = Wf0[(q + 0) * 128 + c];
      const float w1 = Wf0[(q + 1) * 128 + c];
      const float w2 = Wf0[(q + 2) * 128 + c];
      const float w3 = Wf0[(q + 3) * 128 + c];
#pragma unroll
      for (int r = 0; r < 16; ++r) {
        const float4 h = *(const float4*)&hd0s[rh + r][q];
        acc[r] = fmaf(h.x, w0, fmaf(h.y, w1, fmaf(h.z, w2, fmaf(h.w, w3, acc[r]))));
      }
    }
    const size_t g0i = ((size_t)(b * M1 + m0 + rh)) * 128 + c;
#pragma unroll
    for (int r = 0; r < 16; ++r) fdec[g0i + (size_t)r * 128] = acc[r];
  }
  if (t < 96) {
    const int m = t / 3;
    const int c = t - m * 3;
    float acc = 0.0f;
    for (int q = 0; q < 256; ++q) acc = fmaf(hd0s[m][q], wp0s[q * 3 + c], acc);
    out_out1[((size_t)(b * M1 + m0 + m)) * 3 + c] = acc * 0.5f;
  }
}

// ---------------- decoder 1: per-anchor folding MLP -> out0 -----------------
__global__ __launch_bounds__(256) void dec1_kernel(
    const float* __restrict__ fdec, const float* __restrict__ grid1,
    const float* __restrict__ Wd1a, const float* __restrict__ bd1a,
    const float* __restrict__ Wp1, const float* __restrict__ out1r,
    float* __restrict__ out0w) {
  const int a0 = blockIdx.x * 16;
  __shared__ __align__(16) float fds[16][128];
  __shared__ __align__(16) float gs[16][128];
  __shared__ __align__(16) float us[16][128];
  __shared__ __align__(16) float wp1t[3][128];
  __shared__ float o1s[16][3];
  const int t = threadIdx.x;
  {
    const int r = t >> 4;
    const int c0 = (t & 15) * 8;
    const float* src = fdec + ((size_t)(a0 + r)) * 128 + c0;
#pragma unroll
    for (int u = 0; u < 8; ++u) fds[r][c0 + u] = src[u];
  }
  {
    const int k = t >> 4;
    const int c0 = (t & 15) * 8;
    const float g0 = grid1[k * 2 + 0];
    const float g1 = grid1[k * 2 + 1];
#pragma unroll
    for (int u = 0; u < 8; ++u) {
      const int c = c0 + u;
      gs[k][c] = fmaf(g0, Wd1a[128 * 128 + c], fmaf(g1, Wd1a[129 * 128 + c], bd1a[c]));
    }
  }
  if (t < 128) {
    wp1t[0][t] = Wp1[t * 3 + 0];
    wp1t[1][t] = Wp1[t * 3 + 1];
    wp1t[2][t] = Wp1[t * 3 + 2];
  }
  if (t < 48) {
    const int r = t / 3, c = t - r * 3;
    o1s[r][c] = out1r[((size_t)(a0 + r)) * 3 + c];
  }
  __syncthreads();
  {
    const int c = t & 127;
    const int mh = (t >> 7) * 8;
    float acc[8];
#pragma unroll
    for (int r = 0; r < 8; ++r) acc[r] = 0.0f;
    for (int q = 0; q < 128; q += 4) {
      const float w0 = Wd1a[(q + 0) * 128 + c];
      const float w1 = Wd1a[(q + 1) * 128 + c];
      const float w2 = Wd1a[(q + 2) * 128 + c];
      const float w3 = Wd1a[(q + 3) * 128 + c];
#pragma unroll
      for (int r = 0; r < 8; ++r) {
        const float4 f = *(const float4*)&fds[mh + r][q];
        acc[r] = fmaf(f.x, w0, fmaf(f.y, w1, fmaf(f.z, w2, fmaf(f.w, w3, acc[r]))));
      }
    }
#pragma unroll
    for (int r = 0; r < 8; ++r) us[mh + r][c] = acc[r];
  }
  __syncthreads();
  {
    const int m = t >> 4, k = t & 15;
    float a0v = 0.0f, a1v = 0.0f, a2v = 0.0f;
    for (int c = 0; c < 128; c += 4) {
      const float4 uu = *(const float4*)&us[m][c];
      const float4 gg = *(const float4*)&gs[k][c];
      const float h0 = fmaxf(uu.x + gg.x, 0.0f);
      const float h1 = fmaxf(uu.y + gg.y, 0.0f);
      const float h2 = fmaxf(uu.z + gg.z, 0.0f);
      const float h3 = fmaxf(uu.w + gg.w, 0.0f);
      const float4 wx = *(const float4*)&wp1t[0][c];
      const float4 wy = *(const float4*)&wp1t[1][c];
      const float4 wz = *(const float4*)&wp1t[2][c];
      a0v = fmaf(h0, wx.x, fmaf(h1, wx.y, fmaf(h2, wx.z, fmaf(h3, wx.w, a0v))));
      a1v = fmaf(h0, wy.x, fmaf(h1, wy.y, fmaf(h2, wy.z, fmaf(h3, wy.w, a1v))));
      a2v = fmaf(h0, wz.x, fmaf(h1, wz.y, fmaf(h2, wz.z, fmaf(h3, wz.w, a2v))));
    }
    const size_t o = (((size_t)(a0 + m)) * 16 + k) * 3;
    out0w[o + 0] = o1s[m][0] + a0v * 0.2f;
    out0w[o + 1] = o1s[m][1] + a1v * 0.2f;
    out0w[o + 2] = o1s[m][2] + a2v * 0.2f;
  }
}

extern "C" void kernel_launch(void* const* d_in, const int* in_sizes, int n_in,
                              void* d_out_v, int out_size, void* d_ws,
                              size_t ws_size, hipStream_t stream) {
  (void)in_sizes; (void)n_in; (void)out_size; (void)ws_size;
  const float* points = (const float*)d_in[0];
  const float* W0a = (const float*)d_in[1];
  const float* b0a = (const float*)d_in[2];
  const float* W0b = (const float*)d_in[3];
  const float* b0b = (const float*)d_in[4];
  const float* W1a = (const float*)d_in[5];
  const float* b1a = (const float*)d_in[6];
  const float* W1b = (const float*)d_in[7];
  const float* b1b = (const float*)d_in[8];
  const float* grid0 = (const float*)d_in[9];
  const float* Wd0a = (const float*)d_in[10];
  const float* bd0a = (const float*)d_in[11];
  const float* Wp0 = (const float*)d_in[12];
  const float* Wf0 = (const float*)d_in[13];
  const float* grid1 = (const float*)d_in[14];
  const float* Wd1a = (const float*)d_in[15];
  const float* bd1a = (const float*)d_in[16];
  const float* Wp1 = (const float*)d_in[17];
  float* out = (float*)d_out_v;
  char* ws = (char*)d_ws;

  int* fidx = (int*)(ws + 0);
  int* knn_i = (int*)(ws + 32768);
  float* knn_d = (float*)(ws + 557056);
  float* p1 = (float*)(ws + 1081344);
  float* f0 = (float*)(ws + 1179648);
  float* X1 = (float*)(ws + 5373952);
  float* mid1 = (float*)(ws + 9699328);
  float* pmax = (float*)(ws + 18087936);
  float* zW = (float*)(ws + 18366464);
  float* fdec = (float*)(ws + 18374656);

  fps_kernel<<<NB, 1024, 0, stream>>>(points, fidx);
  gather_p1_kernel<<<(NA * 3 + 255) / 256, 256, 0, stream>>>(points, fidx, p1,
                                                             out + OUT_IP1);
  knn_kernel<<<NA / 4, 256, 0, stream>>>(points, p1, knn_i, knn_d,
                                         out + OUT_IP0);
  enc0_kernel<<<NA, 128, 0, stream>>>(out + OUT_IP0, knn_d, p1, W0a, b0a, W0b,
                                      b0b, f0);
  build_x1_kernel<<<(NA * 132 + 255) / 256, 256, 0, stream>>>(p1, f0, X1);
  gemm64_kernel<1, 0><<<dim3(4, 128), 256, 0, stream>>>(X1, W1a, b1a, mid1,
                                                        256, 132, 131, 132, 256);
  gemm64_kernel<0, 1><<<dim3(8, 128), 256, 0, stream>>>(mid1, W1b, b1b, pmax,
                                                        512, 256, 256, 256, 512);
  zwfused_kernel<<<NB, 1024, 0, stream>>>(pmax, Wd0a, out + OUT_Z, zW);
  dec0_kernel<<<256, 256, 0, stream>>>(zW, grid0, Wd0a, bd0a, Wf0, Wp0, fdec,
                                       out + OUT_OUT1);
  dec1_kernel<<<NA / 16, 256, 0, stream>>>(fdec, grid1, Wd1a, bd1a, Wp1,
                                           out + OUT_OUT1, out + OUT_OUT0);
}